// Round 1
// baseline (949.999 us; speedup 1.0000x reference)
//
#include <hip/hip_runtime.h>

// ---------------------------------------------------------------------------
// StandAttention: out = softmax_causal((xWq+bq)(xWk+bk)^T / sqrt(d)) (xWv+bv) Wo + bo
// b=4, s=4096, d=1024. fp32 in/out, bf16 MFMA compute (threshold 7.9e-2).
//
// Pipeline (all on `stream`, batch loop serialized to reuse scratch):
//   1. cast x -> bf16
//   2. transpose-cast Wq/Wk/Wv/Wo -> bf16 W^T (so every GEMM is A[M,K] @ Bt[N,K]^T)
//   3. q/k/v = proj GEMMs (bias fused, bf16 out)
//   4. v -> v^T (bf16 LDS-tiled transpose)
//   5. per batch: scores = q k^T (fp32, into d_out as scratch, above-diag tiles skipped)
//                 softmax (causal, bf16 attn, zeros above diag)
//                 ctx = attn @ v  (K-loop clamped to tile_m+128)
//   6. out = ctx Wo^T + bo (fp32 -> d_out)
//
// GEMM: m97 structure. 128x128 tile, BK=64, 256 thr = 4 waves (2x2 of 64x64),
// global_load_lds width 16 (LDS dest = wave-uniform base + lane*16 -> no padding),
// mfma_f32_16x16x32_bf16, A-frag row=lane&15 k=quad*8+j, C/D col=lane&15 row=quad*4+reg.
// ---------------------------------------------------------------------------

typedef unsigned short u16;
typedef __attribute__((ext_vector_type(4))) unsigned short u16x4;
typedef __attribute__((ext_vector_type(8))) __bf16 bf16x8;
typedef __attribute__((ext_vector_type(4))) float f32x4;

typedef const __attribute__((address_space(1))) void* as1cp;
typedef __attribute__((address_space(3))) void* as3p;

__device__ __forceinline__ u16 f2bf(float f) {
  union { float f; unsigned int i; } c; c.f = f;
  unsigned int r = c.i + 0x7fffu + ((c.i >> 16) & 1u);   // RNE
  return (u16)(r >> 16);
}

// ---------------- cast fp32 -> bf16 (vectorized) ----------------
__global__ __launch_bounds__(256) void cast_f32_bf16(const float* __restrict__ in,
                                                     u16* __restrict__ out, int n4) {
  int i = blockIdx.x * blockDim.x + threadIdx.x;
  if (i >= n4) return;
  float4 v = ((const float4*)in)[i];
  u16x4 u;
  u.x = f2bf(v.x); u.y = f2bf(v.y); u.z = f2bf(v.z); u.w = f2bf(v.w);
  ((u16x4*)out)[i] = u;
}

// ---------------- LDS-tiled transpose (-> bf16) ----------------
// out[c*R + r] = bf16(in[r*C + c]); 32x32 tiles, block (32,8)
template <bool IN_F32>
__global__ __launch_bounds__(256) void transpose_to_bf16(const void* __restrict__ in,
                                                         u16* __restrict__ out,
                                                         int R, int C,
                                                         long inBS, long outBS) {
  __shared__ u16 t[32][34];   // 34: tx*17 mod 32 distinct -> conflict-free col reads
  int b = blockIdx.z;
  int tx = threadIdx.x, ty = threadIdx.y;
  int c0 = blockIdx.x * 32, r0 = blockIdx.y * 32;
#pragma unroll
  for (int dy = 0; dy < 4; ++dy) {
    int r = r0 + ty + dy * 8;
    int c = c0 + tx;
    u16 hv;
    if (IN_F32) hv = f2bf(((const float*)in + (size_t)b * inBS)[(size_t)r * C + c]);
    else        hv = ((const u16*)in + (size_t)b * inBS)[(size_t)r * C + c];
    t[ty + dy * 8][tx] = hv;
  }
  __syncthreads();
  u16* op = out + (size_t)b * outBS;
#pragma unroll
  for (int dy = 0; dy < 4; ++dy) {
    int a = ty + dy * 8;
    op[(size_t)(c0 + a) * R + r0 + tx] = t[tx][a];
  }
}

// ---------------- causal softmax: fp32 scores row -> bf16 attn row ----------------
__global__ __launch_bounds__(256) void softmax_causal(const float* __restrict__ S,
                                                      u16* __restrict__ P) {
  const int SLEN = 4096;
  int row = blockIdx.x;
  int tid = threadIdx.x;
  int lane = tid & 63, wv = tid >> 6;
  const float4* srow = (const float4*)(S + (size_t)row * SLEN);
  const float scale = 0.03125f;  // 1/sqrt(1024)
  float vals[16];
  float lmax = -3.0e38f;
#pragma unroll
  for (int c = 0; c < 4; ++c) {
    int i4 = tid + c * 256;
    float4 v = srow[i4];
    int j = i4 * 4;
    vals[c * 4 + 0] = (j + 0 <= row) ? v.x : -3.0e38f;
    vals[c * 4 + 1] = (j + 1 <= row) ? v.y : -3.0e38f;
    vals[c * 4 + 2] = (j + 2 <= row) ? v.z : -3.0e38f;
    vals[c * 4 + 3] = (j + 3 <= row) ? v.w : -3.0e38f;
    lmax = fmaxf(lmax, fmaxf(fmaxf(vals[c * 4], vals[c * 4 + 1]),
                             fmaxf(vals[c * 4 + 2], vals[c * 4 + 3])));
  }
  __shared__ float red[8];
#pragma unroll
  for (int off = 32; off > 0; off >>= 1) lmax = fmaxf(lmax, __shfl_down(lmax, off, 64));
  if (lane == 0) red[wv] = lmax;
  __syncthreads();
  float rmax = fmaxf(fmaxf(red[0], red[1]), fmaxf(red[2], red[3]));
  float m2 = rmax * scale;
  float lsum = 0.f;
#pragma unroll
  for (int e = 0; e < 16; ++e) {
    float ev = __expf(vals[e] * scale - m2);  // masked: exp(-9e36) == 0
    vals[e] = ev;
    lsum += ev;
  }
#pragma unroll
  for (int off = 32; off > 0; off >>= 1) lsum += __shfl_down(lsum, off, 64);
  if (lane == 0) red[4 + wv] = lsum;
  __syncthreads();
  float inv = 1.0f / (red[4] + red[5] + red[6] + red[7]);
  u16x4* prow = (u16x4*)(P + (size_t)row * SLEN);
#pragma unroll
  for (int c = 0; c < 4; ++c) {
    u16x4 u;
    u.x = f2bf(vals[c * 4 + 0] * inv);
    u.y = f2bf(vals[c * 4 + 1] * inv);
    u.z = f2bf(vals[c * 4 + 2] * inv);
    u.w = f2bf(vals[c * 4 + 3] * inv);
    prow[tid + c * 256] = u;
  }
}

// ---------------- MFMA GEMM: C[M,N] = A[M,K] @ Bt[N,K]^T (+bias) ----------------
template <bool OUT_BF16, bool HAS_BIAS, bool CAUSAL_SKIP, bool CAUSAL_KMAX>
__global__ __launch_bounds__(256) void gemm_bt(const u16* __restrict__ A,
                                               const u16* __restrict__ B,
                                               const float* __restrict__ bias,
                                               void* __restrict__ Cv,
                                               int M, int N, int K) {
  __shared__ __align__(16) u16 As[128 * 64];
  __shared__ __align__(16) u16 Bs[128 * 64];
  int bx = CAUSAL_KMAX ? (gridDim.x - 1 - blockIdx.x) : blockIdx.x;  // heavy tiles first
  int tile_m = bx * 128;
  int tile_n = blockIdx.y * 128;
  if (CAUSAL_SKIP && tile_n >= tile_m + 128) return;  // fully above diagonal, never read

  int tid = threadIdx.x;
  int lane = tid & 63;
  int wv = tid >> 6;
  int wm = (wv >> 1) * 64;
  int wn = (wv & 1) * 64;
  int lrow = lane & 15;
  int lquad = lane >> 4;
  // staging: chunk c = wv*4+t covers LDS bytes [c*1024, +1024) = 8 rows of 64 bf16;
  // lane i -> row c*8 + i/8, cols (i%8)*8 .. +8 (16B contiguous in global along K)
  int srow = lane >> 3;
  int scol = (lane & 7) * 8;
  int kmax = CAUSAL_KMAX ? min(K, tile_m + 128) : K;

  f32x4 acc[4][4];
#pragma unroll
  for (int i = 0; i < 4; ++i)
#pragma unroll
    for (int j = 0; j < 4; ++j) acc[i][j] = (f32x4){0.f, 0.f, 0.f, 0.f};

  for (int k0 = 0; k0 < kmax; k0 += 64) {
#pragma unroll
    for (int t = 0; t < 4; ++t) {
      int c = wv * 4 + t;
      int ar = c * 8 + srow;
      const u16* ga = A + (size_t)(tile_m + ar) * K + k0 + scol;
      __builtin_amdgcn_global_load_lds((as1cp)ga, (as3p)&As[c * 512], 16, 0, 0);
      const u16* gb = B + (size_t)(tile_n + ar) * K + k0 + scol;
      __builtin_amdgcn_global_load_lds((as1cp)gb, (as3p)&Bs[c * 512], 16, 0, 0);
    }
    asm volatile("s_waitcnt vmcnt(0)" ::: "memory");
    __syncthreads();
#pragma unroll
    for (int ks = 0; ks < 64; ks += 32) {
      bf16x8 af[4], bg[4];
#pragma unroll
      for (int mt = 0; mt < 4; ++mt)
        af[mt] = *(const bf16x8*)&As[(wm + mt * 16 + lrow) * 64 + ks + lquad * 8];
#pragma unroll
      for (int nt = 0; nt < 4; ++nt)
        bg[nt] = *(const bf16x8*)&Bs[(wn + nt * 16 + lrow) * 64 + ks + lquad * 8];
#pragma unroll
      for (int mt = 0; mt < 4; ++mt)
#pragma unroll
        for (int nt = 0; nt < 4; ++nt)
          acc[mt][nt] = __builtin_amdgcn_mfma_f32_16x16x32_bf16(af[mt], bg[nt], acc[mt][nt], 0, 0, 0);
    }
    __syncthreads();
  }

#pragma unroll
  for (int mt = 0; mt < 4; ++mt) {
#pragma unroll
    for (int reg = 0; reg < 4; ++reg) {
      int r = tile_m + wm + mt * 16 + lquad * 4 + reg;
#pragma unroll
      for (int nt = 0; nt < 4; ++nt) {
        int cidx = tile_n + wn + nt * 16 + lrow;
        float vvv = acc[mt][nt][reg];
        if (HAS_BIAS) vvv += bias[cidx];
        if (OUT_BF16) ((u16*)Cv)[(size_t)r * N + cidx] = f2bf(vvv);
        else          ((float*)Cv)[(size_t)r * N + cidx] = vvv;
      }
    }
  }
}

// ---------------------------------------------------------------------------
extern "C" void kernel_launch(void* const* d_in, const int* in_sizes, int n_in,
                              void* d_out, int out_size, void* d_ws, size_t ws_size,
                              hipStream_t stream) {
  const float* x  = (const float*)d_in[0];
  const float* Wq = (const float*)d_in[1];
  const float* bq = (const float*)d_in[2];
  const float* Wk = (const float*)d_in[3];
  const float* bk = (const float*)d_in[4];
  const float* Wv = (const float*)d_in[5];
  const float* bv = (const float*)d_in[6];
  const float* Wo = (const float*)d_in[7];
  const float* bo = (const float*)d_in[8];

  const int S = 4096, D = 1024, BATCH = 4;
  const size_t TOK = (size_t)BATCH * S;          // 16384
  const size_t XE = TOK * D;                     // 16.7M elems
  const size_t BSE = (size_t)S * D;              // 4.19M per batch

  char* ws = (char*)d_ws;
  u16* xb  = (u16*)(ws + 0);                     // [16384,1024]; later reused as v^T
  u16* q   = (u16*)(ws + 33554432);
  u16* k   = (u16*)(ws + 67108864);
  u16* v   = (u16*)(ws + 100663296);
  u16* ctx = (u16*)(ws + 134217728);
  u16* wqT = (u16*)(ws + 167772160);
  u16* wkT = wqT + 1048576;
  u16* wvT = wkT + 1048576;
  u16* woT = wvT + 1048576;
  u16* attn = (u16*)(ws + 176160768);            // [4096,4096] bf16, per-batch reuse
  float* scores = (float*)d_out;                 // 64MB scratch == out_size, overwritten last
  u16* vT = xb;                                  // xb dead after projections

  // 1. cast x
  cast_f32_bf16<<<(int)(XE / 4 / 256), 256, 0, stream>>>(x, xb, (int)(XE / 4));
  // 2. weight transposes (fp32 [K,N] -> bf16 [N,K])
  dim3 tb(32, 8);
  transpose_to_bf16<true><<<dim3(32, 32, 1), tb, 0, stream>>>(Wq, wqT, D, D, 0, 0);
  transpose_to_bf16<true><<<dim3(32, 32, 1), tb, 0, stream>>>(Wk, wkT, D, D, 0, 0);
  transpose_to_bf16<true><<<dim3(32, 32, 1), tb, 0, stream>>>(Wv, wvT, D, D, 0, 0);
  transpose_to_bf16<true><<<dim3(32, 32, 1), tb, 0, stream>>>(Wo, woT, D, D, 0, 0);
  // 3. projections
  gemm_bt<true, true, false, false><<<dim3(128, 8), 256, 0, stream>>>(xb, wqT, bq, q, 16384, D, D);
  gemm_bt<true, true, false, false><<<dim3(128, 8), 256, 0, stream>>>(xb, wkT, bk, k, 16384, D, D);
  gemm_bt<true, true, false, false><<<dim3(128, 8), 256, 0, stream>>>(xb, wvT, bv, v, 16384, D, D);
  // 4. v -> v^T per batch ([4096,1024] -> [1024,4096]); overwrites xb (dead)
  transpose_to_bf16<false><<<dim3(D / 32, S / 32, BATCH), tb, 0, stream>>>(
      v, vT, S, D, (long)BSE, (long)BSE);
  // 5. attention, batch-serialized (scores/attn scratch reuse is stream-ordered)
  for (int b = 0; b < BATCH; ++b) {
    const u16* qb = q + (size_t)b * BSE;
    const u16* kb = k + (size_t)b * BSE;
    const u16* vTb = vT + (size_t)b * BSE;
    u16* ctxb = ctx + (size_t)b * BSE;
    gemm_bt<false, false, true, false><<<dim3(32, 32), 256, 0, stream>>>(
        qb, kb, nullptr, scores, S, S, D);
    softmax_causal<<<S, 256, 0, stream>>>(scores, attn);
    gemm_bt<true, false, false, true><<<dim3(32, 8), 256, 0, stream>>>(
        attn, vTb, nullptr, ctxb, S, D, S);
  }
  // 6. output projection (fp32 -> d_out)
  gemm_bt<false, true, false, false><<<dim3(128, 8), 256, 0, stream>>>(
      ctx, woT, bo, d_out, 16384, D, D);
}

// Round 2
// 653.910 us; speedup vs baseline: 1.4528x; 1.4528x over previous
//
#include <hip/hip_runtime.h>

// ---------------------------------------------------------------------------
// StandAttention: out = softmax_causal((xWq+bq)(xWk+bk)^T / sqrt(d)) (xWv+bv) Wo + bo
// b=4, s=4096, d=1024. fp32 in/out, bf16 MFMA compute.
//
// R2 changes vs R1:
//  - all phases batch-parallel via grid.z (PV was 256 blocks = 1/CU, 32x imbalance)
//  - scores stored as *scaled bf16* directly from GEMM epilogue; softmax in-place
//    (allows all-4-batch parallelism in ~208MB ws: attn0/1 in d_out, attn3 over dead v)
//  - XOR bank swizzle on LDS tiles: global source col-block = (lane&7)^(lane>>3),
//    reader XORs col-block with row&7 (global_load_lds dest is fixed lane*16,
//    so the swizzle must ride on the *source* address)
// ---------------------------------------------------------------------------

typedef unsigned short u16;
typedef __attribute__((ext_vector_type(4))) unsigned short u16x4;
typedef __attribute__((ext_vector_type(8))) unsigned short u16x8;
typedef __attribute__((ext_vector_type(8))) __bf16 bf16x8;
typedef __attribute__((ext_vector_type(4))) float f32x4;

typedef const __attribute__((address_space(1))) void* as1cp;
typedef __attribute__((address_space(3))) void* as3p;

struct GemmPtrs {
  const u16* A[4];
  const u16* B[4];
  const float* bias[4];
  void* C[4];
};
struct TransPtrs {
  const void* in[4];
  u16* out[4];
};
struct SmPtrs {
  u16* P[4];
};

__device__ __forceinline__ u16 f2bf(float f) {
  union { float f; unsigned int i; } c; c.f = f;
  unsigned int r = c.i + 0x7fffu + ((c.i >> 16) & 1u);   // RNE
  return (u16)(r >> 16);
}
__device__ __forceinline__ float bf2f(u16 u) {
  union { unsigned int i; float f; } c; c.i = ((unsigned int)u) << 16;
  return c.f;
}

// ---------------- cast fp32 -> bf16 (vectorized) ----------------
__global__ __launch_bounds__(256) void cast_f32_bf16(const float* __restrict__ in,
                                                     u16* __restrict__ out, int n4) {
  int i = blockIdx.x * blockDim.x + threadIdx.x;
  if (i >= n4) return;
  float4 v = ((const float4*)in)[i];
  u16x4 u;
  u.x = f2bf(v.x); u.y = f2bf(v.y); u.z = f2bf(v.z); u.w = f2bf(v.w);
  ((u16x4*)out)[i] = u;
}

// ---------------- LDS-tiled transpose (-> bf16), batched by z ----------------
// out[c*R + r] = bf16(in[r*C + c]); 32x32 tiles, block (32,8)
template <bool IN_F32>
__global__ __launch_bounds__(256) void transpose_to_bf16(TransPtrs tp, int R, int C) {
  __shared__ u16 t[32][34];
  int z = blockIdx.z;
  int tx = threadIdx.x, ty = threadIdx.y;
  int c0 = blockIdx.x * 32, r0 = blockIdx.y * 32;
#pragma unroll
  for (int dy = 0; dy < 4; ++dy) {
    int r = r0 + ty + dy * 8;
    int c = c0 + tx;
    u16 hv;
    if (IN_F32) hv = f2bf(((const float*)tp.in[z])[(size_t)r * C + c]);
    else        hv = ((const u16*)tp.in[z])[(size_t)r * C + c];
    t[ty + dy * 8][tx] = hv;
  }
  __syncthreads();
  u16* op = tp.out[z];
#pragma unroll
  for (int dy = 0; dy < 4; ++dy) {
    int a = ty + dy * 8;
    op[(size_t)(c0 + a) * R + r0 + tx] = t[tx][a];
  }
}

// ---------------- causal softmax, in-place on bf16 scaled scores ----------------
__global__ __launch_bounds__(256) void softmax_causal(SmPtrs sp) {
  const int SLEN = 4096;
  int row = blockIdx.x;
  u16* P = sp.P[blockIdx.y];
  int tid = threadIdx.x;
  int lane = tid & 63, wv = tid >> 6;
  u16x8* prow = (u16x8*)(P + (size_t)row * SLEN);
  float vals[16];
  float lmax = -3.0e38f;
#pragma unroll
  for (int c = 0; c < 2; ++c) {
    int i8 = tid + c * 256;
    u16x8 u = prow[i8];
    int j = i8 * 8;
#pragma unroll
    for (int e = 0; e < 8; ++e) {
      float f = (j + e <= row) ? bf2f(u[e]) : -3.0e38f;
      vals[c * 8 + e] = f;
      lmax = fmaxf(lmax, f);
    }
  }
  __shared__ float red[8];
#pragma unroll
  for (int off = 32; off > 0; off >>= 1) lmax = fmaxf(lmax, __shfl_down(lmax, off, 64));
  if (lane == 0) red[wv] = lmax;
  __syncthreads();
  float m2 = fmaxf(fmaxf(red[0], red[1]), fmaxf(red[2], red[3]));
  float lsum = 0.f;
#pragma unroll
  for (int e = 0; e < 16; ++e) {
    float ev = __expf(vals[e] - m2);   // masked: exp(-huge) == 0
    vals[e] = ev;
    lsum += ev;
  }
#pragma unroll
  for (int off = 32; off > 0; off >>= 1) lsum += __shfl_down(lsum, off, 64);
  if (lane == 0) red[4 + wv] = lsum;
  __syncthreads();
  float inv = 1.0f / (red[4] + red[5] + red[6] + red[7]);
#pragma unroll
  for (int c = 0; c < 2; ++c) {
    u16x8 u;
#pragma unroll
    for (int e = 0; e < 8; ++e) u[e] = f2bf(vals[c * 8 + e] * inv);
    prow[tid + c * 256] = u;
  }
}

// ---------------- MFMA GEMM: C[M,N] = A[M,K] @ Bt[N,K]^T (+bias), *cscale ----------------
// 128x128 tile, BK=64, 4 waves (2x2 of 64x64), global_load_lds width 16,
// XOR-swizzled LDS: phys col-block = logical ^ (row&7).
template <bool OUT_BF16, bool HAS_BIAS, bool CAUSAL_SKIP, bool CAUSAL_KMAX>
__global__ __launch_bounds__(256) void gemm_bt(GemmPtrs p, int M, int N, int K,
                                               float cscale) {
  __shared__ __align__(16) u16 As[128 * 64];
  __shared__ __align__(16) u16 Bs[128 * 64];
  int z = blockIdx.z;
  const u16* __restrict__ A = p.A[z];
  const u16* __restrict__ B = p.B[z];
  int bx = CAUSAL_KMAX ? (gridDim.x - 1 - blockIdx.x) : blockIdx.x;  // heavy first
  int tile_m = bx * 128;
  int tile_n = blockIdx.y * 128;
  if (CAUSAL_SKIP && tile_n >= tile_m + 128) return;  // above diagonal, never read

  int tid = threadIdx.x;
  int lane = tid & 63;
  int wv = tid >> 6;
  int wm = (wv >> 1) * 64;
  int wn = (wv & 1) * 64;
  int lrow = lane & 15;
  int lquad = lane >> 4;
  // staging: chunk c = wv*4+t -> LDS [c*1024B, +1024B); lane l -> phys row c*8+(l>>3),
  // phys col-block l&7, which holds LOGICAL col-block (l&7)^(l>>3) (swizzle on source)
  int srow = lane >> 3;
  int scol = ((lane & 7) ^ srow) * 8;
  int kmax = CAUSAL_KMAX ? min(K, tile_m + 128) : K;

  f32x4 acc[4][4];
#pragma unroll
  for (int i = 0; i < 4; ++i)
#pragma unroll
    for (int j = 0; j < 4; ++j) acc[i][j] = (f32x4){0.f, 0.f, 0.f, 0.f};

  for (int k0 = 0; k0 < kmax; k0 += 64) {
#pragma unroll
    for (int t = 0; t < 4; ++t) {
      int c = wv * 4 + t;
      int ar = c * 8 + srow;
      const u16* ga = A + (size_t)(tile_m + ar) * K + k0 + scol;
      __builtin_amdgcn_global_load_lds((as1cp)ga, (as3p)&As[c * 512], 16, 0, 0);
      const u16* gb = B + (size_t)(tile_n + ar) * K + k0 + scol;
      __builtin_amdgcn_global_load_lds((as1cp)gb, (as3p)&Bs[c * 512], 16, 0, 0);
    }
    asm volatile("s_waitcnt vmcnt(0)" ::: "memory");
    __syncthreads();
#pragma unroll
    for (int ks = 0; ks < 64; ks += 32) {
      bf16x8 af[4], bg[4];
#pragma unroll
      for (int mt = 0; mt < 4; ++mt) {
        int r = wm + mt * 16 + lrow;
        int jb = (ks >> 3) + lquad;
        af[mt] = *(const bf16x8*)&As[r * 64 + ((jb ^ (r & 7)) << 3)];
      }
#pragma unroll
      for (int nt = 0; nt < 4; ++nt) {
        int r = wn + nt * 16 + lrow;
        int jb = (ks >> 3) + lquad;
        bg[nt] = *(const bf16x8*)&Bs[r * 64 + ((jb ^ (r & 7)) << 3)];
      }
#pragma unroll
      for (int mt = 0; mt < 4; ++mt)
#pragma unroll
        for (int nt = 0; nt < 4; ++nt)
          acc[mt][nt] = __builtin_amdgcn_mfma_f32_16x16x32_bf16(af[mt], bg[nt], acc[mt][nt], 0, 0, 0);
    }
    __syncthreads();
  }

  const float* bias = HAS_BIAS ? p.bias[z] : nullptr;
#pragma unroll
  for (int mt = 0; mt < 4; ++mt) {
#pragma unroll
    for (int reg = 0; reg < 4; ++reg) {
      int r = tile_m + wm + mt * 16 + lquad * 4 + reg;
#pragma unroll
      for (int nt = 0; nt < 4; ++nt) {
        int cidx = tile_n + wn + nt * 16 + lrow;
        float vvv = acc[mt][nt][reg] * cscale;
        if (HAS_BIAS) vvv += bias[cidx];
        if (OUT_BF16) ((u16*)p.C[z])[(size_t)r * N + cidx] = f2bf(vvv);
        else          ((float*)p.C[z])[(size_t)r * N + cidx] = vvv;
      }
    }
  }
}

// ---------------------------------------------------------------------------
extern "C" void kernel_launch(void* const* d_in, const int* in_sizes, int n_in,
                              void* d_out, int out_size, void* d_ws, size_t ws_size,
                              hipStream_t stream) {
  const float* x  = (const float*)d_in[0];
  const float* Wq = (const float*)d_in[1];
  const float* bq = (const float*)d_in[2];
  const float* Wk = (const float*)d_in[3];
  const float* bk = (const float*)d_in[4];
  const float* Wv = (const float*)d_in[5];
  const float* bv = (const float*)d_in[6];
  const float* Wo = (const float*)d_in[7];
  const float* bo = (const float*)d_in[8];

  const int S = 4096, D = 1024, BATCH = 4;
  const size_t XE = (size_t)BATCH * S * D;       // 16.7M elems
  const size_t BSE = (size_t)S * D;              // 4.19M per batch

  char* ws = (char*)d_ws;
  u16* xb  = (u16*)(ws + 0);                     // [16384,1024]; reused as v^T
  u16* q   = (u16*)(ws + 33554432);
  u16* k   = (u16*)(ws + 67108864);
  u16* v   = (u16*)(ws + 100663296);             // dead after vT -> attn3
  u16* ctx = (u16*)(ws + 134217728);
  u16* wqT = (u16*)(ws + 167772160);
  u16* wkT = wqT + 1048576;
  u16* wvT = wkT + 1048576;
  u16* woT = wvT + 1048576;
  u16* attn2 = (u16*)(ws + 176160768);           // [4096,4096] bf16
  u16* attn0 = (u16*)d_out;                      // d_out = 67.1MB, dead until out-proj
  u16* attn1 = attn0 + (size_t)S * S;
  u16* attn3 = v;
  u16* vT = xb;
  u16* attn[4] = {attn0, attn1, attn2, attn3};

  // 1. cast x -> bf16
  cast_f32_bf16<<<(int)(XE / 4 / 256), 256, 0, stream>>>(x, xb, (int)(XE / 4));

  // 2. weight transposes, one z=4 dispatch
  dim3 tb(32, 8);
  {
    TransPtrs tp = {{Wq, Wk, Wv, Wo}, {wqT, wkT, wvT, woT}};
    transpose_to_bf16<true><<<dim3(32, 32, 4), tb, 0, stream>>>(tp, D, D);
  }
  // 3. q/k/v projections, one z=3 dispatch
  {
    GemmPtrs gp = {{xb, xb, xb, xb}, {wqT, wkT, wvT, wqT},
                   {bq, bk, bv, bq}, {q, k, v, q}};
    gemm_bt<true, true, false, false><<<dim3(128, 8, 3), 256, 0, stream>>>(
        gp, 16384, D, D, 1.0f);
  }
  // 4. v -> v^T per batch (overwrites dead xb), one z=4 dispatch
  {
    TransPtrs tp = {{v, v + BSE, v + 2 * BSE, v + 3 * BSE},
                    {vT, vT + BSE, vT + 2 * BSE, vT + 3 * BSE}};
    transpose_to_bf16<false><<<dim3(D / 32, S / 32, 4), tb, 0, stream>>>(tp, S, D);
  }
  // 5. scores = (q k^T) * scale -> bf16 attn_z, one z=4 dispatch (skip above-diag)
  {
    GemmPtrs gp = {{q, q + BSE, q + 2 * BSE, q + 3 * BSE},
                   {k, k + BSE, k + 2 * BSE, k + 3 * BSE},
                   {nullptr, nullptr, nullptr, nullptr},
                   {attn[0], attn[1], attn[2], attn[3]}};
    gemm_bt<true, false, true, false><<<dim3(32, 32, 4), 256, 0, stream>>>(
        gp, S, S, D, 0.03125f);
  }
  // 6. causal softmax in-place, one dispatch
  {
    SmPtrs sp = {{attn[0], attn[1], attn[2], attn[3]}};
    softmax_causal<<<dim3(S, 4), 256, 0, stream>>>(sp);
  }
  // 7. ctx = attn @ v (K clamped to tile_m+128), one z=4 dispatch
  {
    GemmPtrs gp = {{attn[0], attn[1], attn[2], attn[3]},
                   {vT, vT + BSE, vT + 2 * BSE, vT + 3 * BSE},
                   {nullptr, nullptr, nullptr, nullptr},
                   {ctx, ctx + BSE, ctx + 2 * BSE, ctx + 3 * BSE}};
    gemm_bt<true, false, false, true><<<dim3(32, 8, 4), 256, 0, stream>>>(
        gp, S, D, S, 1.0f);
  }
  // 8. out = ctx Wo^T + bo (fp32 -> d_out, overwrites attn0/1 which are dead)
  {
    GemmPtrs gp = {{ctx, ctx, ctx, ctx}, {woT, woT, woT, woT},
                   {bo, bo, bo, bo}, {d_out, d_out, d_out, d_out}};
    gemm_bt<false, true, false, false><<<dim3(128, 8, 1), 256, 0, stream>>>(
        gp, 16384, D, D, 1.0f);
  }
}

// Round 3
// 627.775 us; speedup vs baseline: 1.5133x; 1.0416x over previous
//
#include <hip/hip_runtime.h>

// ---------------------------------------------------------------------------
// StandAttention: out = softmax_causal((xWq+bq)(xWk+bk)^T / sqrt(d)) (xWv+bv) Wo + bo
// b=4, s=4096, d=1024. fp32 in/out, bf16 MFMA compute.
//
// R3 changes vs R2 (R2: 654 us, PV GEMM occupancy 12% = 1 block/CU, MfmaUtil 17%):
//  - gemm_bt: explicit double-buffered LDS (2x32KB) with cross-barrier prefetch:
//    stage(k+1) -> other buffer, s_waitcnt vmcnt(8) (prefetch stays in flight),
//    raw s_barrier (no __syncthreads -> no compiler vmcnt(0) drain), compute, barrier.
//  - softmax: causal-trimmed (reads/writes only j<=row + zeros fringe to the 128
//    boundary that PV's kmax clamp reads).
//  - v^T produced directly by GEMM (A=Wv^T, B=x, M=1024, N=16384, row bias);
//    PV reads it with ldb=16384. The separate transpose kernel is gone.
// ---------------------------------------------------------------------------

typedef unsigned short u16;
typedef __attribute__((ext_vector_type(4))) unsigned short u16x4;
typedef __attribute__((ext_vector_type(8))) unsigned short u16x8;
typedef __attribute__((ext_vector_type(8))) __bf16 bf16x8;
typedef __attribute__((ext_vector_type(4))) float f32x4;

typedef const __attribute__((address_space(1))) void* as1cp;
typedef __attribute__((address_space(3))) void* as3p;

struct GemmPtrs {
  const u16* A[4];
  const u16* B[4];
  const float* bias[4];
  void* C[4];
};
struct TransPtrs {
  const void* in[4];
  u16* out[4];
};
struct SmPtrs {
  u16* P[4];
};

__device__ __forceinline__ u16 f2bf(float f) {
  union { float f; unsigned int i; } c; c.f = f;
  unsigned int r = c.i + 0x7fffu + ((c.i >> 16) & 1u);   // RNE
  return (u16)(r >> 16);
}
__device__ __forceinline__ float bf2f(u16 u) {
  union { unsigned int i; float f; } c; c.i = ((unsigned int)u) << 16;
  return c.f;
}

// ---------------- cast fp32 -> bf16 (vectorized) ----------------
__global__ __launch_bounds__(256) void cast_f32_bf16(const float* __restrict__ in,
                                                     u16* __restrict__ out, int n4) {
  int i = blockIdx.x * blockDim.x + threadIdx.x;
  if (i >= n4) return;
  float4 v = ((const float4*)in)[i];
  u16x4 u;
  u.x = f2bf(v.x); u.y = f2bf(v.y); u.z = f2bf(v.z); u.w = f2bf(v.w);
  ((u16x4*)out)[i] = u;
}

// ---------------- LDS-tiled transpose fp32 -> bf16 (weights only) ----------------
__global__ __launch_bounds__(256) void transpose_to_bf16(TransPtrs tp, int R, int C) {
  __shared__ u16 t[32][34];
  int z = blockIdx.z;
  int tx = threadIdx.x, ty = threadIdx.y;
  int c0 = blockIdx.x * 32, r0 = blockIdx.y * 32;
#pragma unroll
  for (int dy = 0; dy < 4; ++dy) {
    int r = r0 + ty + dy * 8;
    int c = c0 + tx;
    t[ty + dy * 8][tx] = f2bf(((const float*)tp.in[z])[(size_t)r * C + c]);
  }
  __syncthreads();
  u16* op = tp.out[z];
#pragma unroll
  for (int dy = 0; dy < 4; ++dy) {
    int a = ty + dy * 8;
    op[(size_t)(c0 + a) * R + r0 + tx] = t[tx][a];
  }
}

// ---------------- causal softmax, in-place, trimmed to j<=row ----------------
// Also zeroes the fringe (row, 128-tile boundary) that the PV kmax clamp reads.
__global__ __launch_bounds__(256) void softmax_causal(SmPtrs sp) {
  int row = blockIdx.x;
  u16* P = sp.P[blockIdx.y];
  int tid = threadIdx.x;
  int lane = tid & 63, wv = tid >> 6;
  u16x8* prow = (u16x8*)(P + (size_t)row * 4096);
  int nch = (row >> 3) + 1;           // vec8 chunks containing any j<=row
  int fend = ((row >> 7) + 1) << 4;   // chunks up to the 128-aligned boundary
  int c0 = tid, c1 = tid + 256;
  bool a0 = c0 < nch, a1 = c1 < nch;
  float vals[16];
  float lmax = -3.0e38f;
  if (a0) {
    u16x8 u = prow[c0];
#pragma unroll
    for (int e = 0; e < 8; ++e) {
      float f = (c0 * 8 + e <= row) ? bf2f(u[e]) : -3.0e38f;
      vals[e] = f; lmax = fmaxf(lmax, f);
    }
  } else {
#pragma unroll
    for (int e = 0; e < 8; ++e) vals[e] = -3.0e38f;
  }
  if (a1) {
    u16x8 u = prow[c1];
#pragma unroll
    for (int e = 0; e < 8; ++e) {
      float f = (c1 * 8 + e <= row) ? bf2f(u[e]) : -3.0e38f;
      vals[8 + e] = f; lmax = fmaxf(lmax, f);
    }
  } else {
#pragma unroll
    for (int e = 0; e < 8; ++e) vals[8 + e] = -3.0e38f;
  }
  __shared__ float red[8];
#pragma unroll
  for (int off = 32; off > 0; off >>= 1) lmax = fmaxf(lmax, __shfl_down(lmax, off, 64));
  if (lane == 0) red[wv] = lmax;
  __syncthreads();
  float m2 = fmaxf(fmaxf(red[0], red[1]), fmaxf(red[2], red[3]));
  float lsum = 0.f;
#pragma unroll
  for (int e = 0; e < 16; ++e) {
    float ev = __expf(vals[e] - m2);   // masked: exp(-huge) == 0
    vals[e] = ev;
    lsum += ev;
  }
#pragma unroll
  for (int off = 32; off > 0; off >>= 1) lsum += __shfl_down(lsum, off, 64);
  if (lane == 0) red[4 + wv] = lsum;
  __syncthreads();
  float inv = 1.0f / (red[4] + red[5] + red[6] + red[7]);
  if (a0) {
    u16x8 u;
#pragma unroll
    for (int e = 0; e < 8; ++e) u[e] = f2bf(vals[e] * inv);
    prow[c0] = u;
  }
  if (a1) {
    u16x8 u;
#pragma unroll
    for (int e = 0; e < 8; ++e) u[e] = f2bf(vals[8 + e] * inv);
    prow[c1] = u;
  }
  u16x8 zz = (u16x8)(u16)0;
  for (int c = nch + tid; c < fend; c += 256) prow[c] = zz;
}

// ---------------- MFMA GEMM: C[M,N] = A[M,K] @ Bt[N,K]^T (+bias), *cscale ----------------
// 128x128 tile, BK=64, 4 waves, double-buffered LDS with cross-barrier prefetch.
// BIAS_MODE: 0=none, 1=per-column (bias[cidx]), 2=per-row (bias[r]).
template <bool OUT_BF16, int BIAS_MODE, bool CAUSAL_SKIP, bool CAUSAL_KMAX>
__global__ __launch_bounds__(256) void gemm_bt(GemmPtrs p, int M, int N, int K,
                                               int ldb, float cscale) {
  __shared__ __align__(16) u16 As[2][128 * 64];
  __shared__ __align__(16) u16 Bs[2][128 * 64];
  int z = blockIdx.z;
  const u16* __restrict__ A = p.A[z];
  const u16* __restrict__ B = p.B[z];
  int bx = CAUSAL_KMAX ? (gridDim.x - 1 - blockIdx.x) : blockIdx.x;  // heavy first
  int tile_m = bx * 128;
  int tile_n = blockIdx.y * 128;
  if (CAUSAL_SKIP && tile_n >= tile_m + 128) return;  // above diagonal, never read

  int tid = threadIdx.x;
  int lane = tid & 63;
  int wv = tid >> 6;
  int wm = (wv >> 1) * 64;
  int wn = (wv & 1) * 64;
  int lrow = lane & 15;
  int lquad = lane >> 4;
  // staging: chunk c = wv*4+t -> LDS [c*1024B,+1024B); lane l -> phys row c*8+(l>>3),
  // phys col-block l&7 holding LOGICAL col-block (l&7)^(l>>3) (XOR bank swizzle on source)
  int srow = lane >> 3;
  int scol = ((lane & 7) ^ srow) * 8;
  int kmax = CAUSAL_KMAX ? min(K, tile_m + 128) : K;
  int niter = kmax >> 6;

  auto stage = [&](int k0, int sb) {
#pragma unroll
    for (int t = 0; t < 4; ++t) {
      int c = wv * 4 + t;
      int ar = c * 8 + srow;
      const u16* ga = A + (size_t)(tile_m + ar) * K + k0 + scol;
      __builtin_amdgcn_global_load_lds((as1cp)ga, (as3p)&As[sb][c * 512], 16, 0, 0);
      const u16* gb = B + (size_t)(tile_n + ar) * (size_t)ldb + k0 + scol;
      __builtin_amdgcn_global_load_lds((as1cp)gb, (as3p)&Bs[sb][c * 512], 16, 0, 0);
    }
  };

  f32x4 acc[4][4];
#pragma unroll
  for (int i = 0; i < 4; ++i)
#pragma unroll
    for (int j = 0; j < 4; ++j) acc[i][j] = (f32x4){0.f, 0.f, 0.f, 0.f};

  stage(0, 0);
  for (int it = 0; it < niter; ++it) {
    int cur = it & 1;
    if (it + 1 < niter) {
      stage((it + 1) << 6, cur ^ 1);
      asm volatile("s_waitcnt vmcnt(8)" ::: "memory");  // cur's 8 landed; prefetch in flight
    } else {
      asm volatile("s_waitcnt vmcnt(0)" ::: "memory");
    }
    asm volatile("s_barrier" ::: "memory");
#pragma unroll
    for (int ks = 0; ks < 64; ks += 32) {
      bf16x8 af[4], bg[4];
#pragma unroll
      for (int mt = 0; mt < 4; ++mt) {
        int r = wm + mt * 16 + lrow;
        int jb = (ks >> 3) + lquad;
        af[mt] = *(const bf16x8*)&As[cur][r * 64 + ((jb ^ (r & 7)) << 3)];
      }
#pragma unroll
      for (int nt = 0; nt < 4; ++nt) {
        int r = wn + nt * 16 + lrow;
        int jb = (ks >> 3) + lquad;
        bg[nt] = *(const bf16x8*)&Bs[cur][r * 64 + ((jb ^ (r & 7)) << 3)];
      }
#pragma unroll
      for (int mt = 0; mt < 4; ++mt)
#pragma unroll
        for (int nt = 0; nt < 4; ++nt)
          acc[mt][nt] = __builtin_amdgcn_mfma_f32_16x16x32_bf16(af[mt], bg[nt], acc[mt][nt], 0, 0, 0);
    }
    asm volatile("s_barrier" ::: "memory");  // done reading cur; next iter overwrites it
  }

#pragma unroll
  for (int mt = 0; mt < 4; ++mt) {
#pragma unroll
    for (int reg = 0; reg < 4; ++reg) {
      int r = tile_m + wm + mt * 16 + lquad * 4 + reg;
      float rb = (BIAS_MODE == 2) ? p.bias[z][r] : 0.f;
#pragma unroll
      for (int nt = 0; nt < 4; ++nt) {
        int cidx = tile_n + wn + nt * 16 + lrow;
        float vvv = acc[mt][nt][reg] * cscale + rb;
        if (BIAS_MODE == 1) vvv += p.bias[z][cidx];
        if (OUT_BF16) ((u16*)p.C[z])[(size_t)r * N + cidx] = f2bf(vvv);
        else          ((float*)p.C[z])[(size_t)r * N + cidx] = vvv;
      }
    }
  }
}

// ---------------------------------------------------------------------------
extern "C" void kernel_launch(void* const* d_in, const int* in_sizes, int n_in,
                              void* d_out, int out_size, void* d_ws, size_t ws_size,
                              hipStream_t stream) {
  const float* x  = (const float*)d_in[0];
  const float* Wq = (const float*)d_in[1];
  const float* bq = (const float*)d_in[2];
  const float* Wk = (const float*)d_in[3];
  const float* bk = (const float*)d_in[4];
  const float* Wv = (const float*)d_in[5];
  const float* bv = (const float*)d_in[6];
  const float* Wo = (const float*)d_in[7];
  const float* bo = (const float*)d_in[8];

  const int S = 4096, D = 1024, BATCH = 4;
  const size_t XE = (size_t)BATCH * S * D;       // 16.7M elems
  const size_t BSE = (size_t)S * D;              // 4.19M per batch

  char* ws = (char*)d_ws;
  u16* xb  = (u16*)(ws + 0);                     // [16384,1024]; dead after projs -> attn3
  u16* q   = (u16*)(ws + 33554432);
  u16* k   = (u16*)(ws + 67108864);
  u16* vT  = (u16*)(ws + 100663296);             // [1024,16384], cols = b*4096+s
  u16* ctx = (u16*)(ws + 134217728);
  u16* wqT = (u16*)(ws + 167772160);
  u16* wkT = wqT + 1048576;
  u16* wvT = wkT + 1048576;
  u16* woT = wvT + 1048576;
  u16* attn2 = (u16*)(ws + 176160768);           // [4096,4096] bf16
  u16* attn0 = (u16*)d_out;                      // d_out 67MB, dead until out-proj
  u16* attn1 = attn0 + (size_t)S * S;
  u16* attn3 = xb;                               // xb dead once q/k/vT are built
  u16* attn[4] = {attn0, attn1, attn2, attn3};

  // 1. cast x -> bf16
  cast_f32_bf16<<<(int)(XE / 4 / 256), 256, 0, stream>>>(x, xb, (int)(XE / 4));

  // 2. weight transposes, one z=4 dispatch
  {
    TransPtrs tp = {{Wq, Wk, Wv, Wo}, {wqT, wkT, wvT, woT}};
    transpose_to_bf16<<<dim3(32, 32, 4), dim3(32, 8), 0, stream>>>(tp, D, D);
  }
  // 3a. q/k projections, one z=2 dispatch
  {
    GemmPtrs gp = {{xb, xb, xb, xb}, {wqT, wkT, wqT, wqT},
                   {bq, bk, bq, bq}, {q, k, q, q}};
    gemm_bt<true, 1, false, false><<<dim3(128, 8, 2), 256, 0, stream>>>(
        gp, 16384, D, D, D, 1.0f);
  }
  // 3b. v^T directly: vT[d, tok] = sum_k Wv[k,d] x[tok,k] + bv[d]
  {
    GemmPtrs gp = {{wvT, wvT, wvT, wvT}, {xb, xb, xb, xb},
                   {bv, bv, bv, bv}, {vT, vT, vT, vT}};
    gemm_bt<true, 2, false, false><<<dim3(8, 128, 1), 256, 0, stream>>>(
        gp, D, 16384, D, D, 1.0f);
  }
  // 4. scores = (q k^T) * scale -> bf16 attn_z (skip above-diag tiles)
  {
    GemmPtrs gp = {{q, q + BSE, q + 2 * BSE, q + 3 * BSE},
                   {k, k + BSE, k + 2 * BSE, k + 3 * BSE},
                   {nullptr, nullptr, nullptr, nullptr},
                   {attn[0], attn[1], attn[2], attn[3]}};
    gemm_bt<true, 0, true, false><<<dim3(32, 32, 4), 256, 0, stream>>>(
        gp, S, S, D, D, 0.03125f);
  }
  // 5. causal softmax in-place (trimmed + fringe zeros)
  {
    SmPtrs sp = {{attn[0], attn[1], attn[2], attn[3]}};
    softmax_causal<<<dim3(S, 4), 256, 0, stream>>>(sp);
  }
  // 6. ctx = attn @ v (K clamped to tile_m+128); B = vT columns of batch b
  {
    GemmPtrs gp = {{attn[0], attn[1], attn[2], attn[3]},
                   {vT, vT + S, vT + 2 * S, vT + 3 * S},
                   {nullptr, nullptr, nullptr, nullptr},
                   {ctx, ctx + BSE, ctx + 2 * BSE, ctx + 3 * BSE}};
    gemm_bt<true, 0, false, true><<<dim3(32, 8, 4), 256, 0, stream>>>(
        gp, S, D, S, BATCH * S, 1.0f);
  }
  // 7. out = ctx Wo^T + bo (fp32 -> d_out, overwrites attn0/1 which are dead)
  {
    GemmPtrs gp = {{ctx, ctx, ctx, ctx}, {woT, woT, woT, woT},
                   {bo, bo, bo, bo}, {d_out, d_out, d_out, d_out}};
    gemm_bt<false, 1, false, false><<<dim3(128, 8, 1), 256, 0, stream>>>(
        gp, 16384, D, D, D, 1.0f);
  }
}

// Round 4
// 614.784 us; speedup vs baseline: 1.5453x; 1.0211x over previous
//
#include <hip/hip_runtime.h>

// ---------------------------------------------------------------------------
// StandAttention: out = softmax_causal((xWq+bq)(xWk+bk)^T / sqrt(d)) (xWv+bv) Wo + bo
// b=4, s=4096, d=1024. fp32 in/out, bf16 MFMA compute.
//
// R4 changes vs R3 (R3: 628 us, all GEMMs ~450 TF, every pipe <20% => latency/
// amortization-bound, K=1024 gives only 16 iters/block):
//  - PERSISTENT-BLOCK GEMM: grid = 512 (exactly 2 blocks/CU at 64KB LDS); each
//    block walks 2..6 output tiles with a staging cursor that runs ahead of the
//    compute cursor ACROSS tile boundaries -> K-loop never stops; prologue paid
//    once per block; epilogue overlaps the next tile's in-flight prefetch.
//  - PV tiles paired heavy+light (rows i and 31-i) -> every block exactly 66 iters.
//  - v computed as a normal projection (q/k/v in ONE persistent dispatch) + cheap
//    LDS transpose; the skinny M=1024 vT GEMM is gone.
// ---------------------------------------------------------------------------

typedef unsigned short u16;
typedef __attribute__((ext_vector_type(4))) unsigned short u16x4;
typedef __attribute__((ext_vector_type(8))) unsigned short u16x8;
typedef __attribute__((ext_vector_type(8))) __bf16 bf16x8;
typedef __attribute__((ext_vector_type(4))) float f32x4;

typedef const __attribute__((address_space(1))) void* as1cp;
typedef __attribute__((address_space(3))) void* as3p;

struct GemmPtrs {
  const u16* A[4];
  const u16* B[4];
  const float* bias[4];
  void* C[4];
};
struct TransPtrs {
  const void* in[4];
  u16* out[4];
};
struct SmPtrs {
  u16* P[4];
};

__device__ __forceinline__ u16 f2bf(float f) {
  union { float f; unsigned int i; } c; c.f = f;
  unsigned int r = c.i + 0x7fffu + ((c.i >> 16) & 1u);   // RNE
  return (u16)(r >> 16);
}
__device__ __forceinline__ float bf2f(u16 u) {
  union { unsigned int i; float f; } c; c.i = ((unsigned int)u) << 16;
  return c.f;
}

// ---------------- cast fp32 -> bf16 (vectorized) ----------------
__global__ __launch_bounds__(256) void cast_f32_bf16(const float* __restrict__ in,
                                                     u16* __restrict__ out, int n4) {
  int i = blockIdx.x * blockDim.x + threadIdx.x;
  if (i >= n4) return;
  float4 v = ((const float4*)in)[i];
  u16x4 u;
  u.x = f2bf(v.x); u.y = f2bf(v.y); u.z = f2bf(v.z); u.w = f2bf(v.w);
  ((u16x4*)out)[i] = u;
}

// ---------------- LDS-tiled transpose (-> bf16), batched by z ----------------
template <bool IN_F32>
__global__ __launch_bounds__(256) void transpose_to_bf16(TransPtrs tp, int R, int C) {
  __shared__ u16 t[32][34];
  int z = blockIdx.z;
  int tx = threadIdx.x, ty = threadIdx.y;
  int c0 = blockIdx.x * 32, r0 = blockIdx.y * 32;
#pragma unroll
  for (int dy = 0; dy < 4; ++dy) {
    int r = r0 + ty + dy * 8;
    int c = c0 + tx;
    u16 hv;
    if (IN_F32) hv = f2bf(((const float*)tp.in[z])[(size_t)r * C + c]);
    else        hv = ((const u16*)tp.in[z])[(size_t)r * C + c];
    t[ty + dy * 8][tx] = hv;
  }
  __syncthreads();
  u16* op = tp.out[z];
#pragma unroll
  for (int dy = 0; dy < 4; ++dy) {
    int a = ty + dy * 8;
    op[(size_t)(c0 + a) * R + r0 + tx] = t[tx][a];
  }
}

// ---------------- causal softmax, in-place, trimmed to j<=row ----------------
__global__ __launch_bounds__(256) void softmax_causal(SmPtrs sp) {
  int row = blockIdx.x;
  u16* P = sp.P[blockIdx.y];
  int tid = threadIdx.x;
  int lane = tid & 63, wv = tid >> 6;
  u16x8* prow = (u16x8*)(P + (size_t)row * 4096);
  int nch = (row >> 3) + 1;           // vec8 chunks containing any j<=row
  int fend = ((row >> 7) + 1) << 4;   // chunks to the 128 boundary PV reads
  int c0 = tid, c1 = tid + 256;
  bool a0 = c0 < nch, a1 = c1 < nch;
  float vals[16];
  float lmax = -3.0e38f;
  if (a0) {
    u16x8 u = prow[c0];
#pragma unroll
    for (int e = 0; e < 8; ++e) {
      float f = (c0 * 8 + e <= row) ? bf2f(u[e]) : -3.0e38f;
      vals[e] = f; lmax = fmaxf(lmax, f);
    }
  } else {
#pragma unroll
    for (int e = 0; e < 8; ++e) vals[e] = -3.0e38f;
  }
  if (a1) {
    u16x8 u = prow[c1];
#pragma unroll
    for (int e = 0; e < 8; ++e) {
      float f = (c1 * 8 + e <= row) ? bf2f(u[e]) : -3.0e38f;
      vals[8 + e] = f; lmax = fmaxf(lmax, f);
    }
  } else {
#pragma unroll
    for (int e = 0; e < 8; ++e) vals[8 + e] = -3.0e38f;
  }
  __shared__ float red[8];
#pragma unroll
  for (int off = 32; off > 0; off >>= 1) lmax = fmaxf(lmax, __shfl_down(lmax, off, 64));
  if (lane == 0) red[wv] = lmax;
  __syncthreads();
  float m2 = fmaxf(fmaxf(red[0], red[1]), fmaxf(red[2], red[3]));
  float lsum = 0.f;
#pragma unroll
  for (int e = 0; e < 16; ++e) {
    float ev = __expf(vals[e] - m2);
    vals[e] = ev;
    lsum += ev;
  }
#pragma unroll
  for (int off = 32; off > 0; off >>= 1) lsum += __shfl_down(lsum, off, 64);
  if (lane == 0) red[4 + wv] = lsum;
  __syncthreads();
  float inv = 1.0f / (red[4] + red[5] + red[6] + red[7]);
  if (a0) {
    u16x8 u;
#pragma unroll
    for (int e = 0; e < 8; ++e) u[e] = f2bf(vals[e] * inv);
    prow[c0] = u;
  }
  if (a1) {
    u16x8 u;
#pragma unroll
    for (int e = 0; e < 8; ++e) u[e] = f2bf(vals[8 + e] * inv);
    prow[c1] = u;
  }
  u16x8 zz = (u16x8)(u16)0;
  for (int c = nch + tid; c < fend; c += 256) prow[c] = zz;
}

// ---------------- persistent MFMA GEMM: C[M,N] = A[M,K] @ Bt[N,K]^T ----------------
// 128x128 tiles, BK=64, 4 waves, dbuf LDS, cross-barrier prefetch, XOR bank swizzle.
// MODE 0: q/k/v projections  (6 slots, tiles = 3 x [128m x 8n], K=1024)
// MODE 1: causal scores      (4|5 slots, tiles = 4 x 528 lower-tri, K=1024)
// MODE 2: PV                 (2 slots, rows i & 31-i paired -> uniform 66 iters)
// MODE 3: out-projection     (2 slots, tiles = [128m x 8n], K=1024)
template <int MODE, bool OUT_BF16, bool HAS_BIAS, int MAXSLOT>
__global__ __launch_bounds__(256) void gemm_persist(GemmPtrs p, int K, int ldb, int N,
                                                    float cscale) {
  __shared__ __align__(16) u16 As[2][128 * 64];
  __shared__ __align__(16) u16 Bs[2][128 * 64];
  int b = blockIdx.x;
  int tid = threadIdx.x, lane = tid & 63, wv = tid >> 6;
  int wm = (wv >> 1) * 64, wn = (wv & 1) * 64;
  int lrow = lane & 15, lquad = lane >> 4;
  int srow = lane >> 3, scol = ((lane & 7) ^ srow) * 8;

  struct TP { const u16* A; const u16* B; int niter, tm, tn, z; };
  auto tileOf = [&](int s) {
    TP t;
    if (MODE == 0) {
      int tt = s * 512 + b; t.z = tt >> 10; int m = tt & 1023;
      t.tm = (m >> 3) << 7; t.tn = (m & 7) << 7; t.niter = K >> 6;
    } else if (MODE == 1) {
      int tt = (s < 4) ? s * 512 + b : 2048 + b;
      t.z = tt / 528; int L = tt - t.z * 528;
      int i = (int)((__fsqrt_rn(8.f * (float)L + 1.f) - 1.f) * 0.5f);
      while ((i + 1) * (i + 2) / 2 <= L) ++i;
      while (i * (i + 1) / 2 > L) --i;
      t.tm = i << 7; t.tn = (L - ((i * (i + 1)) >> 1)) << 7; t.niter = K >> 6;
    } else if (MODE == 2) {
      int g = b >> 5, w = b & 31; t.z = w >> 3;
      int i = (s == 0) ? 31 - g : g;
      t.tm = i << 7; t.tn = (w & 7) << 7; t.niter = (i + 1) * 2;
    } else {
      int tt = s * 512 + b; t.z = 0;
      t.tm = (tt >> 3) << 7; t.tn = (tt & 7) << 7; t.niter = K >> 6;
    }
    t.A = p.A[t.z] + (size_t)t.tm * K;
    t.B = p.B[t.z] + (size_t)t.tn * ldb;
    return t;
  };
  int nslot = (MODE == 1) ? (b < 64 ? 5 : 4) : MAXSLOT;
  int total = (MODE == 2) ? 66 : nslot * (K >> 6);

  auto stage = [&](const TP& t, int k0, int sb) {
#pragma unroll
    for (int tt = 0; tt < 4; ++tt) {
      int c = wv * 4 + tt;
      int ar = c * 8 + srow;
      const u16* ga = t.A + (size_t)ar * K + k0 + scol;
      __builtin_amdgcn_global_load_lds((as1cp)ga, (as3p)&As[sb][c * 512], 16, 0, 0);
      const u16* gb = t.B + (size_t)ar * ldb + k0 + scol;
      __builtin_amdgcn_global_load_lds((as1cp)gb, (as3p)&Bs[sb][c * 512], 16, 0, 0);
    }
  };

  f32x4 acc[4][4];
#pragma unroll
  for (int i = 0; i < 4; ++i)
#pragma unroll
    for (int j = 0; j < 4; ++j) acc[i][j] = (f32x4){0.f, 0.f, 0.f, 0.f};

  auto epi = [&](const TP& t) {
    const float* bias = HAS_BIAS ? p.bias[t.z] : nullptr;
#pragma unroll
    for (int mt = 0; mt < 4; ++mt) {
#pragma unroll
      for (int reg = 0; reg < 4; ++reg) {
        int r = t.tm + wm + mt * 16 + lquad * 4 + reg;
#pragma unroll
        for (int nt = 0; nt < 4; ++nt) {
          int cidx = t.tn + wn + nt * 16 + lrow;
          float vvv = acc[mt][nt][reg] * cscale;
          if (HAS_BIAS) vvv += bias[cidx];
          if (OUT_BF16) ((u16*)p.C[t.z])[(size_t)r * N + cidx] = f2bf(vvv);
          else          ((float*)p.C[t.z])[(size_t)r * N + cidx] = vvv;
        }
      }
    }
#pragma unroll
    for (int i = 0; i < 4; ++i)
#pragma unroll
      for (int j = 0; j < 4; ++j) acc[i][j] = (f32x4){0.f, 0.f, 0.f, 0.f};
  };

  // staging cursor (runs ahead) + compute cursor
  TP st = tileOf(0);
  int stk = 0, sslot = 0;
  auto adv = [&]() {
    if (++stk == st.niter) {
      stk = 0;
      if (++sslot < nslot) st = tileOf(sslot);
    }
  };
  TP ct = st;
  int cit = 0, cslot = 0;

  stage(st, 0, 0);
  adv();
  for (int it = 0; it < total; ++it) {
    int cb = it & 1;
    if (it + 1 < total) {
      stage(st, stk << 6, cb ^ 1);
      adv();
      asm volatile("s_waitcnt vmcnt(8)" ::: "memory");  // cur landed; prefetch in flight
    } else {
      asm volatile("s_waitcnt vmcnt(0)" ::: "memory");
    }
    asm volatile("s_barrier" ::: "memory");
#pragma unroll
    for (int ks = 0; ks < 64; ks += 32) {
      bf16x8 af[4], bg[4];
#pragma unroll
      for (int mt = 0; mt < 4; ++mt) {
        int r = wm + mt * 16 + lrow;
        int jb = (ks >> 3) + lquad;
        af[mt] = *(const bf16x8*)&As[cb][r * 64 + ((jb ^ (r & 7)) << 3)];
      }
#pragma unroll
      for (int nt = 0; nt < 4; ++nt) {
        int r = wn + nt * 16 + lrow;
        int jb = (ks >> 3) + lquad;
        bg[nt] = *(const bf16x8*)&Bs[cb][r * 64 + ((jb ^ (r & 7)) << 3)];
      }
#pragma unroll
      for (int mt = 0; mt < 4; ++mt)
#pragma unroll
        for (int nt = 0; nt < 4; ++nt)
          acc[mt][nt] = __builtin_amdgcn_mfma_f32_16x16x32_bf16(af[mt], bg[nt], acc[mt][nt], 0, 0, 0);
    }
    asm volatile("s_barrier" ::: "memory");  // all waves done reading cb
    if (++cit == ct.niter) {
      epi(ct);                               // overlaps next tile's in-flight prefetch
      cit = 0;
      if (++cslot < nslot) ct = tileOf(cslot);
    }
  }
}

// ---------------------------------------------------------------------------
extern "C" void kernel_launch(void* const* d_in, const int* in_sizes, int n_in,
                              void* d_out, int out_size, void* d_ws, size_t ws_size,
                              hipStream_t stream) {
  const float* x  = (const float*)d_in[0];
  const float* Wq = (const float*)d_in[1];
  const float* bq = (const float*)d_in[2];
  const float* Wk = (const float*)d_in[3];
  const float* bk = (const float*)d_in[4];
  const float* Wv = (const float*)d_in[5];
  const float* bv = (const float*)d_in[6];
  const float* Wo = (const float*)d_in[7];
  const float* bo = (const float*)d_in[8];

  const int S = 4096, D = 1024;
  const size_t XE = (size_t)4 * S * D;
  const size_t BSE = (size_t)S * D;

  char* ws = (char*)d_ws;
  u16* xb  = (u16*)(ws + 0);                     // [16384,1024]; dead after proj -> vT
  u16* q   = (u16*)(ws + 33554432);
  u16* k   = (u16*)(ws + 67108864);
  u16* v   = (u16*)(ws + 100663296);             // dead after transpose -> attn3
  u16* ctx = (u16*)(ws + 134217728);
  u16* wqT = (u16*)(ws + 167772160);
  u16* wkT = wqT + 1048576;
  u16* wvT = wkT + 1048576;
  u16* woT = wvT + 1048576;
  u16* attn2 = (u16*)(ws + 176160768);           // [4096,4096] bf16
  u16* attn0 = (u16*)d_out;                      // d_out 67MB, dead until out-proj
  u16* attn1 = attn0 + (size_t)S * S;
  u16* attn3 = v;
  u16* vT = xb;                                  // [1024,4096] per batch, contiguous
  u16* attn[4] = {attn0, attn1, attn2, attn3};

  // 1. cast x -> bf16
  cast_f32_bf16<<<(int)(XE / 4 / 256), 256, 0, stream>>>(x, xb, (int)(XE / 4));
  // 2. weight transposes
  {
    TransPtrs tp = {{Wq, Wk, Wv, Wo}, {wqT, wkT, wvT, woT}};
    transpose_to_bf16<true><<<dim3(32, 32, 4), dim3(32, 8), 0, stream>>>(tp, D, D);
  }
  // 3. q/k/v projections, one persistent dispatch (3072 tiles over 512 blocks)
  {
    GemmPtrs gp = {{xb, xb, xb, xb}, {wqT, wkT, wvT, wqT},
                   {bq, bk, bv, bq}, {q, k, v, q}};
    gemm_persist<0, true, true, 6><<<512, 256, 0, stream>>>(gp, D, D, D, 1.0f);
  }
  // 4. v -> v^T per batch (overwrites dead xb)
  {
    TransPtrs tp = {{v, v + BSE, v + 2 * BSE, v + 3 * BSE},
                    {vT, vT + BSE, vT + 2 * BSE, vT + 3 * BSE}};
    transpose_to_bf16<false><<<dim3(D / 32, S / 32, 4), dim3(32, 8), 0, stream>>>(tp, S, D);
  }
  // 5. scores = (q k^T)*scale -> bf16 attn_z (2112 lower-tri tiles over 512 blocks)
  {
    GemmPtrs gp = {{q, q + BSE, q + 2 * BSE, q + 3 * BSE},
                   {k, k + BSE, k + 2 * BSE, k + 3 * BSE},
                   {nullptr, nullptr, nullptr, nullptr},
                   {attn[0], attn[1], attn[2], attn[3]}};
    gemm_persist<1, true, false, 5><<<512, 256, 0, stream>>>(gp, D, D, S, 0.03125f);
  }
  // 6. causal softmax in-place (trimmed + fringe zeros)
  {
    SmPtrs sp = {{attn[0], attn[1], attn[2], attn[3]}};
    softmax_causal<<<dim3(S, 4), 256, 0, stream>>>(sp);
  }
  // 7. ctx = attn @ v (1024 tiles, heavy+light paired -> uniform 66 iters/block)
  {
    GemmPtrs gp = {{attn[0], attn[1], attn[2], attn[3]},
                   {vT, vT + BSE, vT + 2 * BSE, vT + 3 * BSE},
                   {nullptr, nullptr, nullptr, nullptr},
                   {ctx, ctx + BSE, ctx + 2 * BSE, ctx + 3 * BSE}};
    gemm_persist<2, true, false, 2><<<512, 256, 0, stream>>>(gp, S, S, D, 1.0f);
  }
  // 8. out = ctx Wo^T + bo (fp32 -> d_out, overwrites dead attn0/1)
  {
    GemmPtrs gp = {{ctx, ctx, ctx, ctx}, {woT, woT, woT, woT},
                   {bo, bo, bo, bo}, {d_out, d_out, d_out, d_out}};
    gemm_persist<3, false, true, 2><<<512, 256, 0, stream>>>(gp, D, D, D, 1.0f);
  }
}

// Round 5
// 572.936 us; speedup vs baseline: 1.6581x; 1.0730x over previous
//
#include <hip/hip_runtime.h>

// ---------------------------------------------------------------------------
// StandAttention: out = softmax_causal((xWq+bq)(xWk+bk)^T / sqrt(d)) (xWv+bv) Wo + bo
// b=4, s=4096, d=1024. fp32 in/out, bf16 MFMA compute.
//
// R5 changes vs R4 (R4: 615 us; proj dispatch FETCH=401MB vs 38MB ideal -> A rows
// re-fetched by n-tiles living on different XCDs):
//  - XCD-aware co-scheduled tile maps: the 8 n-tiles sharing one A row-block go to
//    8 blocks with the SAME b%8 (same XCD) at the SAME slot -> A fetched once/XCD.
//    proj/scores/outproj: chunk c = (b&7) + 8*(8s + (b>>3)>>... see tileOf.
//    PV: XCD x owns i in {x,15-x,16+x,31-x}, slot pairs (x,31-x)/(15-x,16+x)
//    -> every block exactly 33 chunk-iters (perfect balance).
//  - K/ldb are template constants (strength-reduced staging address math).
// ---------------------------------------------------------------------------

typedef unsigned short u16;
typedef __attribute__((ext_vector_type(4))) unsigned short u16x4;
typedef __attribute__((ext_vector_type(8))) unsigned short u16x8;
typedef __attribute__((ext_vector_type(8))) __bf16 bf16x8;
typedef __attribute__((ext_vector_type(4))) float f32x4;

typedef const __attribute__((address_space(1))) void* as1cp;
typedef __attribute__((address_space(3))) void* as3p;

struct GemmPtrs {
  const u16* A[4];
  const u16* B[4];
  const float* bias[4];
  void* C[4];
};
struct TransPtrs {
  const void* in[4];
  u16* out[4];
};
struct SmPtrs {
  u16* P[4];
};

__device__ __forceinline__ u16 f2bf(float f) {
  union { float f; unsigned int i; } c; c.f = f;
  unsigned int r = c.i + 0x7fffu + ((c.i >> 16) & 1u);   // RNE
  return (u16)(r >> 16);
}
__device__ __forceinline__ float bf2f(u16 u) {
  union { unsigned int i; float f; } c; c.i = ((unsigned int)u) << 16;
  return c.f;
}

// ---------------- cast fp32 -> bf16 (vectorized) ----------------
__global__ __launch_bounds__(256) void cast_f32_bf16(const float* __restrict__ in,
                                                     u16* __restrict__ out, int n4) {
  int i = blockIdx.x * blockDim.x + threadIdx.x;
  if (i >= n4) return;
  float4 v = ((const float4*)in)[i];
  u16x4 u;
  u.x = f2bf(v.x); u.y = f2bf(v.y); u.z = f2bf(v.z); u.w = f2bf(v.w);
  ((u16x4*)out)[i] = u;
}

// ---------------- LDS-tiled transpose (-> bf16), batched by z ----------------
template <bool IN_F32>
__global__ __launch_bounds__(256) void transpose_to_bf16(TransPtrs tp, int R, int C) {
  __shared__ u16 t[32][34];
  int z = blockIdx.z;
  int tx = threadIdx.x, ty = threadIdx.y;
  int c0 = blockIdx.x * 32, r0 = blockIdx.y * 32;
#pragma unroll
  for (int dy = 0; dy < 4; ++dy) {
    int r = r0 + ty + dy * 8;
    int c = c0 + tx;
    u16 hv;
    if (IN_F32) hv = f2bf(((const float*)tp.in[z])[(size_t)r * C + c]);
    else        hv = ((const u16*)tp.in[z])[(size_t)r * C + c];
    t[ty + dy * 8][tx] = hv;
  }
  __syncthreads();
  u16* op = tp.out[z];
#pragma unroll
  for (int dy = 0; dy < 4; ++dy) {
    int a = ty + dy * 8;
    op[(size_t)(c0 + a) * R + r0 + tx] = t[tx][a];
  }
}

// ---------------- causal softmax, in-place, trimmed to j<=row ----------------
__global__ __launch_bounds__(256) void softmax_causal(SmPtrs sp) {
  int row = blockIdx.x;
  u16* P = sp.P[blockIdx.y];
  int tid = threadIdx.x;
  int lane = tid & 63, wv = tid >> 6;
  u16x8* prow = (u16x8*)(P + (size_t)row * 4096);
  int nch = (row >> 3) + 1;           // vec8 chunks containing any j<=row
  int fend = ((row >> 7) + 1) << 4;   // chunks to the 128 boundary PV reads
  int c0 = tid, c1 = tid + 256;
  bool a0 = c0 < nch, a1 = c1 < nch;
  float vals[16];
  float lmax = -3.0e38f;
  if (a0) {
    u16x8 u = prow[c0];
#pragma unroll
    for (int e = 0; e < 8; ++e) {
      float f = (c0 * 8 + e <= row) ? bf2f(u[e]) : -3.0e38f;
      vals[e] = f; lmax = fmaxf(lmax, f);
    }
  } else {
#pragma unroll
    for (int e = 0; e < 8; ++e) vals[e] = -3.0e38f;
  }
  if (a1) {
    u16x8 u = prow[c1];
#pragma unroll
    for (int e = 0; e < 8; ++e) {
      float f = (c1 * 8 + e <= row) ? bf2f(u[e]) : -3.0e38f;
      vals[8 + e] = f; lmax = fmaxf(lmax, f);
    }
  } else {
#pragma unroll
    for (int e = 0; e < 8; ++e) vals[8 + e] = -3.0e38f;
  }
  __shared__ float red[8];
#pragma unroll
  for (int off = 32; off > 0; off >>= 1) lmax = fmaxf(lmax, __shfl_down(lmax, off, 64));
  if (lane == 0) red[wv] = lmax;
  __syncthreads();
  float m2 = fmaxf(fmaxf(red[0], red[1]), fmaxf(red[2], red[3]));
  float lsum = 0.f;
#pragma unroll
  for (int e = 0; e < 16; ++e) {
    float ev = __expf(vals[e] - m2);
    vals[e] = ev;
    lsum += ev;
  }
#pragma unroll
  for (int off = 32; off > 0; off >>= 1) lsum += __shfl_down(lsum, off, 64);
  if (lane == 0) red[4 + wv] = lsum;
  __syncthreads();
  float inv = 1.0f / (red[4] + red[5] + red[6] + red[7]);
  if (a0) {
    u16x8 u;
#pragma unroll
    for (int e = 0; e < 8; ++e) u[e] = f2bf(vals[e] * inv);
    prow[c0] = u;
  }
  if (a1) {
    u16x8 u;
#pragma unroll
    for (int e = 0; e < 8; ++e) u[e] = f2bf(vals[8 + e] * inv);
    prow[c1] = u;
  }
  u16x8 zz = (u16x8)(u16)0;
  for (int c = nch + tid; c < fend; c += 256) prow[c] = zz;
}

// ---------------- persistent MFMA GEMM: C[M,N] = A[M,K] @ Bt[N,K]^T ----------------
// 128x128 tiles, BK=64, 4 waves, dbuf LDS, cross-barrier prefetch, XOR bank swizzle,
// XCD-aware tile maps (XCD = b%8; 8 blocks sharing an A row-block are co-resident).
// MODE 0: q/k/v projections (6 slots)   MODE 1: causal scores (5|4 slots)
// MODE 2: PV (2 slots, 33 iters/block)  MODE 3: out-projection (2 slots)
template <int MODE, bool OUT_BF16, bool HAS_BIAS, int MAXSLOT, int KDIM, int LDB>
__global__ __launch_bounds__(256) void gemm_persist(GemmPtrs p, int N, float cscale) {
  __shared__ __align__(16) u16 As[2][128 * 64];
  __shared__ __align__(16) u16 Bs[2][128 * 64];
  int b = blockIdx.x;
  int x = b & 7, q = b >> 3;                  // x = XCD, q = index on XCD
  int tid = threadIdx.x, lane = tid & 63, wv = tid >> 6;
  int wm = (wv >> 1) * 64, wn = (wv & 1) * 64;
  int lrow = lane & 15, lquad = lane >> 4;
  int srow = lane >> 3, scol = ((lane & 7) ^ srow) * 8;

  struct TP { const u16* A; const u16* B; int niter, tm, tn, z; };
  auto tileOf = [&](int s) {
    TP t;
    if (MODE == 0) {
      int c = x + 8 * (s * 8 + (q >> 3));     // chunk = mat*128 + m, same-XCD group
      t.z = c >> 7;
      t.tm = (c & 127) << 7; t.tn = (q & 7) << 7; t.niter = KDIM >> 6;
    } else if (MODE == 1) {
      int c = x + 8 * (s * 8 + (q >> 3));     // chunk in [0,264)
      int tt = c * 8 + (q & 7);
      t.z = tt / 528; int L = tt - t.z * 528;
      int i = (int)((__fsqrt_rn(8.f * (float)L + 1.f) - 1.f) * 0.5f);
      while ((i + 1) * (i + 2) / 2 <= L) ++i;
      while (i * (i + 1) / 2 > L) --i;
      t.tm = i << 7; t.tn = (L - ((i * (i + 1)) >> 1)) << 7; t.niter = KDIM >> 6;
    } else if (MODE == 2) {
      int w = q & 15, h = w >> 3;
      int i = (s == 0) ? (h ? 15 - x : x) : (h ? 16 + x : 31 - x);
      t.z = q >> 4; t.tm = i << 7; t.tn = (w & 7) << 7; t.niter = (i + 1) * 2;
    } else {
      int c = x + 8 * (s * 8 + (q >> 3));     // chunk = m in [0,128)
      t.z = 0; t.tm = c << 7; t.tn = (q & 7) << 7; t.niter = KDIM >> 6;
    }
    t.A = p.A[t.z] + (size_t)t.tm * KDIM;
    t.B = p.B[t.z] + (size_t)t.tn * LDB;
    return t;
  };
  int nslot = (MODE == 1) ? ((q >> 3) == 0 ? 5 : 4) : MAXSLOT;
  int total = (MODE == 2) ? 66 : nslot * (KDIM >> 6);

  auto stage = [&](const TP& t, int k0, int sb) {
#pragma unroll
    for (int tt = 0; tt < 4; ++tt) {
      int c = wv * 4 + tt;
      int ar = c * 8 + srow;
      const u16* ga = t.A + (size_t)ar * KDIM + k0 + scol;
      __builtin_amdgcn_global_load_lds((as1cp)ga, (as3p)&As[sb][c * 512], 16, 0, 0);
      const u16* gb = t.B + (size_t)ar * LDB + k0 + scol;
      __builtin_amdgcn_global_load_lds((as1cp)gb, (as3p)&Bs[sb][c * 512], 16, 0, 0);
    }
  };

  f32x4 acc[4][4];
#pragma unroll
  for (int i = 0; i < 4; ++i)
#pragma unroll
    for (int j = 0; j < 4; ++j) acc[i][j] = (f32x4){0.f, 0.f, 0.f, 0.f};

  auto epi = [&](const TP& t) {
    const float* bias = HAS_BIAS ? p.bias[t.z] : nullptr;
#pragma unroll
    for (int mt = 0; mt < 4; ++mt) {
#pragma unroll
      for (int reg = 0; reg < 4; ++reg) {
        int r = t.tm + wm + mt * 16 + lquad * 4 + reg;
#pragma unroll
        for (int nt = 0; nt < 4; ++nt) {
          int cidx = t.tn + wn + nt * 16 + lrow;
          float vvv = acc[mt][nt][reg] * cscale;
          if (HAS_BIAS) vvv += bias[cidx];
          if (OUT_BF16) ((u16*)p.C[t.z])[(size_t)r * N + cidx] = f2bf(vvv);
          else          ((float*)p.C[t.z])[(size_t)r * N + cidx] = vvv;
        }
      }
    }
#pragma unroll
    for (int i = 0; i < 4; ++i)
#pragma unroll
      for (int j = 0; j < 4; ++j) acc[i][j] = (f32x4){0.f, 0.f, 0.f, 0.f};
  };

  // staging cursor (runs ahead) + compute cursor
  TP st = tileOf(0);
  int stk = 0, sslot = 0;
  auto adv = [&]() {
    if (++stk == st.niter) {
      stk = 0;
      if (++sslot < nslot) st = tileOf(sslot);
    }
  };
  TP ct = st;
  int cit = 0, cslot = 0;

  stage(st, 0, 0);
  adv();
  for (int it = 0; it < total; ++it) {
    int cb = it & 1;
    if (it + 1 < total) {
      stage(st, stk << 6, cb ^ 1);
      adv();
      asm volatile("s_waitcnt vmcnt(8)" ::: "memory");  // cur landed; prefetch in flight
    } else {
      asm volatile("s_waitcnt vmcnt(0)" ::: "memory");
    }
    asm volatile("s_barrier" ::: "memory");
#pragma unroll
    for (int ks = 0; ks < 64; ks += 32) {
      bf16x8 af[4], bg[4];
#pragma unroll
      for (int mt = 0; mt < 4; ++mt) {
        int r = wm + mt * 16 + lrow;
        int jb = (ks >> 3) + lquad;
        af[mt] = *(const bf16x8*)&As[cb][r * 64 + ((jb ^ (r & 7)) << 3)];
      }
#pragma unroll
      for (int nt = 0; nt < 4; ++nt) {
        int r = wn + nt * 16 + lrow;
        int jb = (ks >> 3) + lquad;
        bg[nt] = *(const bf16x8*)&Bs[cb][r * 64 + ((jb ^ (r & 7)) << 3)];
      }
#pragma unroll
      for (int mt = 0; mt < 4; ++mt)
#pragma unroll
        for (int nt = 0; nt < 4; ++nt)
          acc[mt][nt] = __builtin_amdgcn_mfma_f32_16x16x32_bf16(af[mt], bg[nt], acc[mt][nt], 0, 0, 0);
    }
    asm volatile("s_barrier" ::: "memory");  // all waves done reading cb
    if (++cit == ct.niter) {
      epi(ct);                               // overlaps next tile's in-flight prefetch
      cit = 0;
      if (++cslot < nslot) ct = tileOf(cslot);
    }
  }
}

// ---------------------------------------------------------------------------
extern "C" void kernel_launch(void* const* d_in, const int* in_sizes, int n_in,
                              void* d_out, int out_size, void* d_ws, size_t ws_size,
                              hipStream_t stream) {
  const float* x  = (const float*)d_in[0];
  const float* Wq = (const float*)d_in[1];
  const float* bq = (const float*)d_in[2];
  const float* Wk = (const float*)d_in[3];
  const float* bk = (const float*)d_in[4];
  const float* Wv = (const float*)d_in[5];
  const float* bv = (const float*)d_in[6];
  const float* Wo = (const float*)d_in[7];
  const float* bo = (const float*)d_in[8];

  const int S = 4096, D = 1024;
  const size_t XE = (size_t)4 * S * D;
  const size_t BSE = (size_t)S * D;

  char* ws = (char*)d_ws;
  u16* xb  = (u16*)(ws + 0);                     // [16384,1024]; dead after proj -> vT
  u16* q   = (u16*)(ws + 33554432);
  u16* k   = (u16*)(ws + 67108864);
  u16* v   = (u16*)(ws + 100663296);             // dead after transpose -> attn3
  u16* ctx = (u16*)(ws + 134217728);
  u16* wqT = (u16*)(ws + 167772160);
  u16* wkT = wqT + 1048576;
  u16* wvT = wkT + 1048576;
  u16* woT = wvT + 1048576;
  u16* attn2 = (u16*)(ws + 176160768);           // [4096,4096] bf16
  u16* attn0 = (u16*)d_out;                      // d_out 67MB, dead until out-proj
  u16* attn1 = attn0 + (size_t)S * S;
  u16* attn3 = v;
  u16* vT = xb;                                  // [1024,4096] per batch, contiguous
  u16* attn[4] = {attn0, attn1, attn2, attn3};

  // 1. cast x -> bf16
  cast_f32_bf16<<<(int)(XE / 4 / 256), 256, 0, stream>>>(x, xb, (int)(XE / 4));
  // 2. weight transposes
  {
    TransPtrs tp = {{Wq, Wk, Wv, Wo}, {wqT, wkT, wvT, woT}};
    transpose_to_bf16<true><<<dim3(32, 32, 4), dim3(32, 8), 0, stream>>>(tp, D, D);
  }
  // 3. q/k/v projections, one persistent dispatch (3072 tiles over 512 blocks)
  {
    GemmPtrs gp = {{xb, xb, xb, xb}, {wqT, wkT, wvT, wqT},
                   {bq, bk, bv, bq}, {q, k, v, q}};
    gemm_persist<0, true, true, 6, 1024, 1024><<<512, 256, 0, stream>>>(gp, D, 1.0f);
  }
  // 4. v -> v^T per batch (overwrites dead xb)
  {
    TransPtrs tp = {{v, v + BSE, v + 2 * BSE, v + 3 * BSE},
                    {vT, vT + BSE, vT + 2 * BSE, vT + 3 * BSE}};
    transpose_to_bf16<false><<<dim3(D / 32, S / 32, 4), dim3(32, 8), 0, stream>>>(tp, S, D);
  }
  // 5. scores = (q k^T)*scale -> bf16 attn_z (2112 lower-tri tiles over 512 blocks)
  {
    GemmPtrs gp = {{q, q + BSE, q + 2 * BSE, q + 3 * BSE},
                   {k, k + BSE, k + 2 * BSE, k + 3 * BSE},
                   {nullptr, nullptr, nullptr, nullptr},
                   {attn[0], attn[1], attn[2], attn[3]}};
    gemm_persist<1, true, false, 5, 1024, 1024><<<512, 256, 0, stream>>>(gp, S, 0.03125f);
  }
  // 6. causal softmax in-place (trimmed + fringe zeros)
  {
    SmPtrs sp = {{attn[0], attn[1], attn[2], attn[3]}};
    softmax_causal<<<dim3(S, 4), 256, 0, stream>>>(sp);
  }
  // 7. ctx = attn @ v (1024 tiles; XCD-local i-sets, 33 iters per block)
  {
    GemmPtrs gp = {{attn[0], attn[1], attn[2], attn[3]},
                   {vT, vT + BSE, vT + 2 * BSE, vT + 3 * BSE},
                   {nullptr, nullptr, nullptr, nullptr},
                   {ctx, ctx + BSE, ctx + 2 * BSE, ctx + 3 * BSE}};
    gemm_persist<2, true, false, 2, 4096, 4096><<<512, 256, 0, stream>>>(gp, D, 1.0f);
  }
  // 8. out = ctx Wo^T + bo (fp32 -> d_out, overwrites dead attn0/1)
  {
    GemmPtrs gp = {{ctx, ctx, ctx, ctx}, {woT, woT, woT, woT},
                   {bo, bo, bo, bo}, {d_out, d_out, d_out, d_out}};
    gemm_persist<3, false, true, 2, 1024, 1024><<<512, 256, 0, stream>>>(gp, D, 1.0f);
  }
}

// Round 6
// 512.210 us; speedup vs baseline: 1.8547x; 1.1186x over previous
//
#include <hip/hip_runtime.h>

// ---------------------------------------------------------------------------
// StandAttention: out = softmax_causal((xWq+bq)(xWk+bk)^T / sqrt(d)) (xWv+bv) Wo + bo
// b=4, s=4096, d=1024. fp32 in/out, bf16 MFMA compute.
//
// R6 changes vs R5 (R5: 573 us; proj VALUBusy 54% > MfmaUtil 29% -> VALU-bound on
// per-iter address recomputation):
//  - persistent loop unrolled x2: LDS buffer index is COMPILE-TIME, so all 32
//    ds_read_b128 addresses are loop-invariant (hoisted; buf-1 delta folds into
//    the 16-bit ds offset immediate). All mode totals are even (96/80/64/66/32).
//  - incremental staging pointers gA/gB (+=64 elems/iter) replace per-iter
//    base + ar*K + k0 recomputation; tt deltas are compile-time shifts.
// ---------------------------------------------------------------------------

typedef unsigned short u16;
typedef __attribute__((ext_vector_type(4))) unsigned short u16x4;
typedef __attribute__((ext_vector_type(8))) unsigned short u16x8;
typedef __attribute__((ext_vector_type(8))) __bf16 bf16x8;
typedef __attribute__((ext_vector_type(4))) float f32x4;

typedef const __attribute__((address_space(1))) void* as1cp;
typedef __attribute__((address_space(3))) void* as3p;

struct GemmPtrs {
  const u16* A[4];
  const u16* B[4];
  const float* bias[4];
  void* C[4];
};
struct TransPtrs {
  const void* in[4];
  u16* out[4];
};
struct SmPtrs {
  u16* P[4];
};

__device__ __forceinline__ u16 f2bf(float f) {
  union { float f; unsigned int i; } c; c.f = f;
  unsigned int r = c.i + 0x7fffu + ((c.i >> 16) & 1u);   // RNE
  return (u16)(r >> 16);
}
__device__ __forceinline__ float bf2f(u16 u) {
  union { unsigned int i; float f; } c; c.i = ((unsigned int)u) << 16;
  return c.f;
}

// ---------------- cast fp32 -> bf16 (vectorized) ----------------
__global__ __launch_bounds__(256) void cast_f32_bf16(const float* __restrict__ in,
                                                     u16* __restrict__ out, int n4) {
  int i = blockIdx.x * blockDim.x + threadIdx.x;
  if (i >= n4) return;
  float4 v = ((const float4*)in)[i];
  u16x4 u;
  u.x = f2bf(v.x); u.y = f2bf(v.y); u.z = f2bf(v.z); u.w = f2bf(v.w);
  ((u16x4*)out)[i] = u;
}

// ---------------- LDS-tiled transpose (-> bf16), batched by z ----------------
template <bool IN_F32>
__global__ __launch_bounds__(256) void transpose_to_bf16(TransPtrs tp, int R, int C) {
  __shared__ u16 t[32][34];
  int z = blockIdx.z;
  int tx = threadIdx.x, ty = threadIdx.y;
  int c0 = blockIdx.x * 32, r0 = blockIdx.y * 32;
#pragma unroll
  for (int dy = 0; dy < 4; ++dy) {
    int r = r0 + ty + dy * 8;
    int c = c0 + tx;
    u16 hv;
    if (IN_F32) hv = f2bf(((const float*)tp.in[z])[(size_t)r * C + c]);
    else        hv = ((const u16*)tp.in[z])[(size_t)r * C + c];
    t[ty + dy * 8][tx] = hv;
  }
  __syncthreads();
  u16* op = tp.out[z];
#pragma unroll
  for (int dy = 0; dy < 4; ++dy) {
    int a = ty + dy * 8;
    op[(size_t)(c0 + a) * R + r0 + tx] = t[tx][a];
  }
}

// ---------------- causal softmax, in-place, trimmed to j<=row ----------------
__global__ __launch_bounds__(256) void softmax_causal(SmPtrs sp) {
  int row = blockIdx.x;
  u16* P = sp.P[blockIdx.y];
  int tid = threadIdx.x;
  int lane = tid & 63, wv = tid >> 6;
  u16x8* prow = (u16x8*)(P + (size_t)row * 4096);
  int nch = (row >> 3) + 1;           // vec8 chunks containing any j<=row
  int fend = ((row >> 7) + 1) << 4;   // chunks to the 128 boundary PV reads
  int c0 = tid, c1 = tid + 256;
  bool a0 = c0 < nch, a1 = c1 < nch;
  float vals[16];
  float lmax = -3.0e38f;
  if (a0) {
    u16x8 u = prow[c0];
#pragma unroll
    for (int e = 0; e < 8; ++e) {
      float f = (c0 * 8 + e <= row) ? bf2f(u[e]) : -3.0e38f;
      vals[e] = f; lmax = fmaxf(lmax, f);
    }
  } else {
#pragma unroll
    for (int e = 0; e < 8; ++e) vals[e] = -3.0e38f;
  }
  if (a1) {
    u16x8 u = prow[c1];
#pragma unroll
    for (int e = 0; e < 8; ++e) {
      float f = (c1 * 8 + e <= row) ? bf2f(u[e]) : -3.0e38f;
      vals[8 + e] = f; lmax = fmaxf(lmax, f);
    }
  } else {
#pragma unroll
    for (int e = 0; e < 8; ++e) vals[8 + e] = -3.0e38f;
  }
  __shared__ float red[8];
#pragma unroll
  for (int off = 32; off > 0; off >>= 1) lmax = fmaxf(lmax, __shfl_down(lmax, off, 64));
  if (lane == 0) red[wv] = lmax;
  __syncthreads();
  float m2 = fmaxf(fmaxf(red[0], red[1]), fmaxf(red[2], red[3]));
  float lsum = 0.f;
#pragma unroll
  for (int e = 0; e < 16; ++e) {
    float ev = __expf(vals[e] - m2);
    vals[e] = ev;
    lsum += ev;
  }
#pragma unroll
  for (int off = 32; off > 0; off >>= 1) lsum += __shfl_down(lsum, off, 64);
  if (lane == 0) red[4 + wv] = lsum;
  __syncthreads();
  float inv = 1.0f / (red[4] + red[5] + red[6] + red[7]);
  if (a0) {
    u16x8 u;
#pragma unroll
    for (int e = 0; e < 8; ++e) u[e] = f2bf(vals[e] * inv);
    prow[c0] = u;
  }
  if (a1) {
    u16x8 u;
#pragma unroll
    for (int e = 0; e < 8; ++e) u[e] = f2bf(vals[8 + e] * inv);
    prow[c1] = u;
  }
  u16x8 zz = (u16x8)(u16)0;
  for (int c = nch + tid; c < fend; c += 256) prow[c] = zz;
}

// ---------------- persistent MFMA GEMM: C[M,N] = A[M,K] @ Bt[N,K]^T ----------------
// 128x128 tiles, BK=64, 4 waves, dbuf LDS (compile-time buffer via x2 unroll),
// cross-barrier prefetch, XOR bank swizzle, XCD-aware tile maps, incremental
// staging pointers.
// MODE 0: q/k/v projections (6 slots)   MODE 1: causal scores (5|4 slots)
// MODE 2: PV (2 slots, 33 iters/block)  MODE 3: out-projection (2 slots)
template <int MODE, bool OUT_BF16, bool HAS_BIAS, int MAXSLOT, int KDIM, int LDB>
__global__ __launch_bounds__(256) void gemm_persist(GemmPtrs p, int N, float cscale) {
  __shared__ __align__(16) u16 As[2][128 * 64];
  __shared__ __align__(16) u16 Bs[2][128 * 64];
  int b = blockIdx.x;
  int x = b & 7, q = b >> 3;                  // x = XCD, q = index on XCD
  int tid = threadIdx.x, lane = tid & 63, wv = tid >> 6;
  int wm = (wv >> 1) * 64, wn = (wv & 1) * 64;
  int lrow = lane & 15, lquad = lane >> 4;
  int srow = lane >> 3, scol = ((lane & 7) ^ srow) * 8;

  struct TP { const u16* A; const u16* B; int niter, tm, tn, z; };
  auto tileOf = [&](int s) {
    TP t;
    if (MODE == 0) {
      int c = x + 8 * (s * 8 + (q >> 3));     // chunk = mat*128 + m, same-XCD group
      t.z = c >> 7;
      t.tm = (c & 127) << 7; t.tn = (q & 7) << 7; t.niter = KDIM >> 6;
    } else if (MODE == 1) {
      int c = x + 8 * (s * 8 + (q >> 3));     // chunk in [0,264)
      int tt = c * 8 + (q & 7);
      t.z = tt / 528; int L = tt - t.z * 528;
      int i = (int)((__fsqrt_rn(8.f * (float)L + 1.f) - 1.f) * 0.5f);
      while ((i + 1) * (i + 2) / 2 <= L) ++i;
      while (i * (i + 1) / 2 > L) --i;
      t.tm = i << 7; t.tn = (L - ((i * (i + 1)) >> 1)) << 7; t.niter = KDIM >> 6;
    } else if (MODE == 2) {
      int w = q & 15, h = w >> 3;
      int i = (s == 0) ? (h ? 15 - x : x) : (h ? 16 + x : 31 - x);
      t.z = q >> 4; t.tm = i << 7; t.tn = (w & 7) << 7; t.niter = (i + 1) * 2;
    } else {
      int c = x + 8 * (s * 8 + (q >> 3));     // chunk = m in [0,128)
      t.z = 0; t.tm = c << 7; t.tn = (q & 7) << 7; t.niter = KDIM >> 6;
    }
    t.A = p.A[t.z] + (size_t)t.tm * KDIM;
    t.B = p.B[t.z] + (size_t)t.tn * LDB;
    return t;
  };
  int nslot = (MODE == 1) ? ((q >> 3) == 0 ? 5 : 4) : MAXSLOT;
  int total = (MODE == 2) ? 66 : nslot * (KDIM >> 6);   // always EVEN (96/80/64/66/32)

  // per-lane element offsets within a tile for staging chunk tt=0
  int aoff = (wv * 32 + srow) * KDIM + scol;
  int boff = (wv * 32 + srow) * LDB + scol;

  // staging cursor state (runs one iter ahead of compute)
  TP st = tileOf(0);
  int stk = 0, sslot = 0;
  const u16* gA = st.A + aoff;
  const u16* gB = st.B + boff;

  auto stageTo = [&](int sb) {
#pragma unroll
    for (int tt = 0; tt < 4; ++tt) {
      __builtin_amdgcn_global_load_lds((as1cp)(gA + tt * 8 * KDIM),
                                       (as3p)&As[sb][(wv * 4 + tt) * 512], 16, 0, 0);
      __builtin_amdgcn_global_load_lds((as1cp)(gB + tt * 8 * LDB),
                                       (as3p)&Bs[sb][(wv * 4 + tt) * 512], 16, 0, 0);
    }
  };
  auto adv = [&]() {
    gA += 64; gB += 64;
    if (++stk == st.niter) {
      stk = 0;
      if (++sslot < nslot) {
        st = tileOf(sslot);
        gA = st.A + aoff;
        gB = st.B + boff;
      }
    }
  };

  f32x4 acc[4][4];
#pragma unroll
  for (int i = 0; i < 4; ++i)
#pragma unroll
    for (int j = 0; j < 4; ++j) acc[i][j] = (f32x4){0.f, 0.f, 0.f, 0.f};

  auto compute = [&](int cb) __attribute__((always_inline)) {
#pragma unroll
    for (int ks = 0; ks < 64; ks += 32) {
      bf16x8 af[4], bg[4];
#pragma unroll
      for (int mt = 0; mt < 4; ++mt) {
        int r = wm + mt * 16 + lrow;
        int jb = (ks >> 3) + lquad;
        af[mt] = *(const bf16x8*)&As[cb][r * 64 + ((jb ^ (r & 7)) << 3)];
      }
#pragma unroll
      for (int nt = 0; nt < 4; ++nt) {
        int r = wn + nt * 16 + lrow;
        int jb = (ks >> 3) + lquad;
        bg[nt] = *(const bf16x8*)&Bs[cb][r * 64 + ((jb ^ (r & 7)) << 3)];
      }
#pragma unroll
      for (int mt = 0; mt < 4; ++mt)
#pragma unroll
        for (int nt = 0; nt < 4; ++nt)
          acc[mt][nt] = __builtin_amdgcn_mfma_f32_16x16x32_bf16(af[mt], bg[nt], acc[mt][nt], 0, 0, 0);
    }
  };

  // compute cursor
  TP ct = st;
  int cit = 0, cslot = 0;
  auto epi = [&]() {
    if (++cit == ct.niter) {
      const float* bias = HAS_BIAS ? p.bias[ct.z] : nullptr;
#pragma unroll
      for (int mt = 0; mt < 4; ++mt) {
#pragma unroll
        for (int reg = 0; reg < 4; ++reg) {
          int r = ct.tm + wm + mt * 16 + lquad * 4 + reg;
#pragma unroll
          for (int nt = 0; nt < 4; ++nt) {
            int cidx = ct.tn + wn + nt * 16 + lrow;
            float vvv = acc[mt][nt][reg] * cscale;
            if (HAS_BIAS) vvv += bias[cidx];
            if (OUT_BF16) ((u16*)p.C[ct.z])[(size_t)r * N + cidx] = f2bf(vvv);
            else          ((float*)p.C[ct.z])[(size_t)r * N + cidx] = vvv;
          }
        }
      }
#pragma unroll
      for (int i = 0; i < 4; ++i)
#pragma unroll
        for (int j = 0; j < 4; ++j) acc[i][j] = (f32x4){0.f, 0.f, 0.f, 0.f};
      cit = 0;
      if (++cslot < nslot) ct = tileOf(cslot);
    }
  };

  stageTo(0);
  adv();
  for (int it = 0; it < total; it += 2) {
    // ---- cb = 0 ----
    if (it + 1 < total) {
      stageTo(1);                                       // prefetch into buf 1
      adv();
      asm volatile("s_waitcnt vmcnt(8)" ::: "memory");  // buf-0 loads landed
    } else {
      asm volatile("s_waitcnt vmcnt(0)" ::: "memory");
    }
    asm volatile("s_barrier" ::: "memory");
    compute(0);
    asm volatile("s_barrier" ::: "memory");
    epi();
    // ---- cb = 1 ----
    if (it + 2 < total) {
      stageTo(0);                                       // prefetch into buf 0
      adv();
      asm volatile("s_waitcnt vmcnt(8)" ::: "memory");  // buf-1 loads landed
    } else {
      asm volatile("s_waitcnt vmcnt(0)" ::: "memory");
    }
    asm volatile("s_barrier" ::: "memory");
    compute(1);
    asm volatile("s_barrier" ::: "memory");
    epi();
  }
}

// ---------------------------------------------------------------------------
extern "C" void kernel_launch(void* const* d_in, const int* in_sizes, int n_in,
                              void* d_out, int out_size, void* d_ws, size_t ws_size,
                              hipStream_t stream) {
  const float* x  = (const float*)d_in[0];
  const float* Wq = (const float*)d_in[1];
  const float* bq = (const float*)d_in[2];
  const float* Wk = (const float*)d_in[3];
  const float* bk = (const float*)d_in[4];
  const float* Wv = (const float*)d_in[5];
  const float* bv = (const float*)d_in[6];
  const float* Wo = (const float*)d_in[7];
  const float* bo = (const float*)d_in[8];

  const int S = 4096, D = 1024;
  const size_t XE = (size_t)4 * S * D;
  const size_t BSE = (size_t)S * D;

  char* ws = (char*)d_ws;
  u16* xb  = (u16*)(ws + 0);                     // [16384,1024]; dead after proj -> vT
  u16* q   = (u16*)(ws + 33554432);
  u16* k   = (u16*)(ws + 67108864);
  u16* v   = (u16*)(ws + 100663296);             // dead after transpose -> attn3
  u16* ctx = (u16*)(ws + 134217728);
  u16* wqT = (u16*)(ws + 167772160);
  u16* wkT = wqT + 1048576;
  u16* wvT = wkT + 1048576;
  u16* woT = wvT + 1048576;
  u16* attn2 = (u16*)(ws + 176160768);           // [4096,4096] bf16
  u16* attn0 = (u16*)d_out;                      // d_out 67MB, dead until out-proj
  u16* attn1 = attn0 + (size_t)S * S;
  u16* attn3 = v;
  u16* vT = xb;                                  // [1024,4096] per batch, contiguous
  u16* attn[4] = {attn0, attn1, attn2, attn3};

  // 1. cast x -> bf16
  cast_f32_bf16<<<(int)(XE / 4 / 256), 256, 0, stream>>>(x, xb, (int)(XE / 4));
  // 2. weight transposes
  {
    TransPtrs tp = {{Wq, Wk, Wv, Wo}, {wqT, wkT, wvT, woT}};
    transpose_to_bf16<true><<<dim3(32, 32, 4), dim3(32, 8), 0, stream>>>(tp, D, D);
  }
  // 3. q/k/v projections, one persistent dispatch (3072 tiles over 512 blocks)
  {
    GemmPtrs gp = {{xb, xb, xb, xb}, {wqT, wkT, wvT, wqT},
                   {bq, bk, bv, bq}, {q, k, v, q}};
    gemm_persist<0, true, true, 6, 1024, 1024><<<512, 256, 0, stream>>>(gp, D, 1.0f);
  }
  // 4. v -> v^T per batch (overwrites dead xb)
  {
    TransPtrs tp = {{v, v + BSE, v + 2 * BSE, v + 3 * BSE},
                    {vT, vT + BSE, vT + 2 * BSE, vT + 3 * BSE}};
    transpose_to_bf16<false><<<dim3(D / 32, S / 32, 4), dim3(32, 8), 0, stream>>>(tp, S, D);
  }
  // 5. scores = (q k^T)*scale -> bf16 attn_z (2112 lower-tri tiles over 512 blocks)
  {
    GemmPtrs gp = {{q, q + BSE, q + 2 * BSE, q + 3 * BSE},
                   {k, k + BSE, k + 2 * BSE, k + 3 * BSE},
                   {nullptr, nullptr, nullptr, nullptr},
                   {attn[0], attn[1], attn[2], attn[3]}};
    gemm_persist<1, true, false, 5, 1024, 1024><<<512, 256, 0, stream>>>(gp, S, 0.03125f);
  }
  // 6. causal softmax in-place (trimmed + fringe zeros)
  {
    SmPtrs sp = {{attn[0], attn[1], attn[2], attn[3]}};
    softmax_causal<<<dim3(S, 4), 256, 0, stream>>>(sp);
  }
  // 7. ctx = attn @ v (1024 tiles; XCD-local i-sets, 33 iters per block)
  {
    GemmPtrs gp = {{attn[0], attn[1], attn[2], attn[3]},
                   {vT, vT + BSE, vT + 2 * BSE, vT + 3 * BSE},
                   {nullptr, nullptr, nullptr, nullptr},
                   {ctx, ctx + BSE, ctx + 2 * BSE, ctx + 3 * BSE}};
    gemm_persist<2, true, false, 2, 4096, 4096><<<512, 256, 0, stream>>>(gp, D, 1.0f);
  }
  // 8. out = ctx Wo^T + bo (fp32 -> d_out, overwrites dead attn0/1)
  {
    GemmPtrs gp = {{ctx, ctx, ctx, ctx}, {woT, woT, woT, woT},
                   {bo, bo, bo, bo}, {d_out, d_out, d_out, d_out}};
    gemm_persist<3, false, true, 2, 1024, 1024><<<512, 256, 0, stream>>>(gp, D, 1.0f);
  }
}